// Round 1
// 687.858 us; speedup vs baseline: 1.0284x; 1.0284x over previous
//
#include <hip/hip_runtime.h>

typedef unsigned short u16;
typedef __bf16 bf16x8 __attribute__((ext_vector_type(8)));
typedef float f32x4 __attribute__((ext_vector_type(4)));
typedef unsigned short u16x8 __attribute__((ext_vector_type(8)));

#define NNODES 50000
#define NEDGES 640000
#define NGRAPH 256

__device__ __forceinline__ float bf2f(u16 u) {
  unsigned int v = ((unsigned int)u) << 16; float f; __builtin_memcpy(&f, &v, 4); return f;
}
__device__ __forceinline__ u16 f2bf(float f) {
  unsigned int x; __builtin_memcpy(&x, &f, 4);
  unsigned int lsb = (x >> 16) & 1u;
  x += 0x7fffu + lsb;
  return (u16)(x >> 16);
}

// ---------------- safe fallback: zero fp32 output ---------------------------
__global__ void write_zero_f32(float* __restrict__ out, int n) {
  int i = blockIdx.x * 256 + threadIdx.x;
  if (i < n) out[i] = 0.f;
}

// ---------------- zero-init scratch counters --------------------------------
__global__ void zero_counts(int* __restrict__ a, int na, int* __restrict__ b, int nb) {
  int i = blockIdx.x * 256 + threadIdx.x;
  if (i < na) a[i] = 0;
  if (i < nb) b[i] = 0;
}

// ---------------- weight prep: fp32 -> bf16 transpose (B-layout Wt[n][k]) ---
__global__ void prep_weights(const float* __restrict__ node_w, const float* __restrict__ edge_w1,
                             const float* __restrict__ edge_w2, const float* __restrict__ conv_w1,
                             const float* __restrict__ conv_w2, const float* __restrict__ gate_w1,
                             u16* __restrict__ node_wt, u16* __restrict__ edge_w1t,
                             u16* __restrict__ edge_w2t, u16* __restrict__ conv_w1t,
                             u16* __restrict__ conv_w2t, u16* __restrict__ gate_w1t) {
  int o = blockIdx.x * 256 + threadIdx.x;
  if (o < 8192) { int n = o >> 6, k = o & 63; node_wt[o] = f2bf(node_w[k * 128 + n]); return; }
  o -= 8192;
  if (o < 4096) { int n = o >> 5, k = o & 31;
                  edge_w1t[o] = (k < 16) ? f2bf(edge_w1[k * 128 + n]) : (u16)0; return; }
  o -= 4096;
  if (o < 16384) { int n = o >> 7, k = o & 127; edge_w2t[o] = f2bf(edge_w2[k * 128 + n]); return; }
  o -= 16384;
  if (o < 65536) { int l = o >> 14, r = o & 16383, n = r >> 7, k = r & 127;
                   conv_w1t[o] = f2bf(conv_w1[l * 16384 + k * 128 + n]); return; }
  o -= 65536;
  if (o < 65536) { int l = o >> 14, r = o & 16383, n = r >> 7, k = r & 127;
                   conv_w2t[o] = f2bf(conv_w2[l * 16384 + k * 128 + n]); return; }
  o -= 65536;
  if (o < 8192) { int n = o >> 7, k = o & 127; gate_w1t[o] = f2bf(gate_w1[k * 64 + n]); }
}

// ---------------- CSR build --------------------------------------------------
__global__ void hist_all(const int* __restrict__ dst, const int* __restrict__ b,
                         int* __restrict__ counts, int* __restrict__ gc, int n) {
  int i = blockIdx.x * 256 + threadIdx.x;
  atomicAdd(&counts[dst[i]], 1);
  if (i < n) atomicAdd(&gc[b[i]], 1);
}
__global__ void scan_a(const int* __restrict__ counts, int* __restrict__ bsums, int n) {
  int b = blockIdx.x, t = threadIdx.x;
  int i0 = b * 1024 + t * 4;
  int s = 0;
#pragma unroll
  for (int j = 0; j < 4; j++) { int i = i0 + j; if (i < n) s += counts[i]; }
  int lane = t & 63, w = t >> 6;
  for (int m = 32; m; m >>= 1) s += __shfl_xor(s, m, 64);
  __shared__ int ws_[4];
  if (lane == 0) ws_[w] = s;
  __syncthreads();
  if (t == 0) bsums[b] = ws_[0] + ws_[1] + ws_[2] + ws_[3];
}
__global__ void scan_b(int* __restrict__ bsums, int* __restrict__ offs, int nb, int n) {
  if (threadIdx.x == 0) {
    int run = 0;
    for (int i = 0; i < nb; i++) { int v = bsums[i]; bsums[i] = run; run += v; }
    offs[n] = run;
  }
}
__global__ void scan_c(const int* __restrict__ counts, const int* __restrict__ boffs,
                       int* __restrict__ offs, int* __restrict__ cursor, int n) {
  int b = blockIdx.x, t = threadIdx.x;
  int i0 = b * 1024 + t * 4;
  int v[4]; int s = 0;
#pragma unroll
  for (int j = 0; j < 4; j++) { v[j] = (i0 + j < n) ? counts[i0 + j] : 0; s += v[j]; }
  int lane = t & 63, w = t >> 6;
  int x = s;
  for (int d = 1; d < 64; d <<= 1) { int y = __shfl_up(x, (unsigned)d, 64); if (lane >= d) x += y; }
  __shared__ int wt_[4];
  if (lane == 63) wt_[w] = x;
  __syncthreads();
  int add = boffs[b];
  for (int i = 0; i < w; i++) add += wt_[i];
  int excl = add + x - s;
#pragma unroll
  for (int j = 0; j < 4; j++) {
    int i = i0 + j;
    if (i < n) { offs[i] = excl; cursor[i] = excl; }
    excl += v[j];
  }
}
__global__ void gscan(const int* __restrict__ gcounts, int* __restrict__ goffs) {
  int t = threadIdx.x;  // 256
  int v = gcounts[t];
  int lane = t & 63, w = t >> 6;
  int x = v;
  for (int d = 1; d < 64; d <<= 1) { int y = __shfl_up(x, (unsigned)d, 64); if (lane >= d) x += y; }
  __shared__ int wt_[4];
  if (lane == 63) wt_[w] = x;
  __syncthreads();
  int add = 0;
  for (int i = 0; i < w; i++) add += wt_[i];
  int incl = add + x;
  goffs[t] = incl - v;
  if (t == 255) goffs[256] = incl;
}
__global__ void scatter_csr(const int* __restrict__ src, const int* __restrict__ dst,
                            int* __restrict__ cursor, int* __restrict__ csr_src,
                            int* __restrict__ csr_eid) {
  int i = blockIdx.x * 256 + threadIdx.x;
  int d = dst[i];
  int p = atomicAdd(&cursor[d], 1);
  csr_src[p] = src[i];
  csr_eid[p] = i;
}

// ---------------- MFMA tile helper (A,B both from LDS) ----------------------
template <int KB, int SA, int SB>
__device__ __forceinline__ void mfma_block(const u16* aL, const u16* bL, int m, int quad,
                                           int rbase, f32x4* acc) {
#pragma unroll
  for (int kb = 0; kb < KB; ++kb) {
    bf16x8 a = *(const bf16x8*)(aL + (rbase + m) * SA + kb * 32 + quad * 8);
#pragma unroll
    for (int nt = 0; nt < 8; ++nt) {
      bf16x8 b = *(const bf16x8*)(bL + (nt * 16 + m) * SB + kb * 32 + quad * 8);
      acc[nt] = __builtin_amdgcn_mfma_f32_16x16x32_bf16(a, b, acc[nt], 0, 0, 0);
    }
  }
}

// ---------------- node encoder: hb = bf16(x @ node_w + node_b) --------------
__global__ __launch_bounds__(256) void node_encode(const float* __restrict__ x,
                                                   const u16* __restrict__ wt,
                                                   const float* __restrict__ nb,
                                                   u16* __restrict__ hb, int n) {
  __shared__ alignas(16) u16 sA[64 * 72];
  __shared__ alignas(16) u16 sW[128 * 72];
  int t = threadIdx.x;
  int row0 = blockIdx.x * 64;
#pragma unroll
  for (int i = 0; i < 4; i++) {
    int idx = t + 256 * i; int r = idx >> 4, c = idx & 15;  // 64 rows x 16 float4 (K=64)
    int grow = row0 + r; if (grow > n - 1) grow = n - 1;
    float4 v = *(const float4*)(x + (size_t)grow * 64 + c * 4);
    ushort4 o; o.x = f2bf(v.x); o.y = f2bf(v.y); o.z = f2bf(v.z); o.w = f2bf(v.w);
    *(ushort4*)&sA[r * 72 + c * 4] = o;
  }
#pragma unroll
  for (int i = 0; i < 4; i++) {
    int idx = t + 256 * i; int nr = idx >> 3, c = idx & 7;  // 128 rows x 8 uint4 (K=64)
    *(uint4*)&sW[nr * 72 + c * 8] = *(const uint4*)(wt + nr * 64 + c * 8);
  }
  __syncthreads();
  int lane = t & 63, w = t >> 6, m = lane & 15, quad = lane >> 4, rbase = w * 16;
  f32x4 acc[8];
  f32x4 z4 = {0.f, 0.f, 0.f, 0.f};
#pragma unroll
  for (int i = 0; i < 8; i++) acc[i] = z4;
  mfma_block<2, 72, 72>(sA, sW, m, quad, rbase, acc);
#pragma unroll
  for (int nt = 0; nt < 8; nt++) {
    int col = nt * 16 + m;
    float bb = nb[col];
    f32x4 a4 = acc[nt];
#pragma unroll
    for (int r = 0; r < 4; r++) {
      int grow = row0 + rbase + quad * 4 + r;
      if (grow < n) hb[(size_t)grow * 128 + col] = f2bf(a4[r] + bb);
    }
  }
}

// ---------------- edge encoder v8: swapped GEMM2 -> direct packed stores ----
// GEMM2 computed as D^T = W2^T x Mid^T (operand-swapped MFMA): lane then holds
// 4 consecutive output channels (quad*4+r) of one edge (m) per acc reg group,
// so the epilogue is 8B register->global stores. Removes the post-GEMM2 LDS
// pack, 2 barriers, and the LDS->global copy pass of v7.
__global__ __launch_bounds__(256) void edge_encode(const float* __restrict__ ea,
                                                   const u16* __restrict__ w1t,
                                                   const u16* __restrict__ w2t,
                                                   const float* __restrict__ b1,
                                                   const float* __restrict__ b2,
                                                   const int* __restrict__ csr_eid,
                                                   u16* __restrict__ e_perm) {
  __shared__ alignas(16) u16 sA[64 * 48];     // K padded 16->32
  __shared__ alignas(16) u16 sMid[64 * 136];  // GEMM1 out / GEMM2 in
  int t = threadIdx.x;
  int lane = t & 63, w = t >> 6, m = lane & 15, quad = lane >> 4, rbase = w * 16;
  int s0 = blockIdx.x * 64;

  if (t < 128) {
    int r = t >> 1, c = t & 1;
    uint4 z = {0, 0, 0, 0};
    *(uint4*)&sA[r * 48 + 16 + c * 8] = z;
  }
  {
    int eidv = 0;
    if (lane < 16) eidv = csr_eid[s0 + w * 16 + lane];
    int r = lane >> 2, c = lane & 3;
    int eid = __shfl(eidv, r, 64);
    float4 v = *(const float4*)(ea + (size_t)eid * 16 + c * 4);
    ushort4 o; o.x = f2bf(v.x); o.y = f2bf(v.y); o.z = f2bf(v.z); o.w = f2bf(v.w);
    *(ushort4*)&sA[(w * 16 + r) * 48 + c * 4] = o;
  }
  bf16x8 w1f[8];
  float b1r[8];
#pragma unroll
  for (int nt = 0; nt < 8; nt++) {
    w1f[nt] = *(const bf16x8*)(w1t + (nt * 16 + m) * 32 + quad * 8);
    b1r[nt] = b1[nt * 16 + m];
  }
  __syncthreads();  // b1: sA complete

  f32x4 z4 = {0.f, 0.f, 0.f, 0.f};
  f32x4 acc[8];
#pragma unroll
  for (int i = 0; i < 8; i++) acc[i] = z4;
  {
    bf16x8 a = *(const bf16x8*)(&sA[(rbase + m) * 48 + quad * 8]);
#pragma unroll
    for (int nt = 0; nt < 8; nt++)
      acc[nt] = __builtin_amdgcn_mfma_f32_16x16x32_bf16(a, w1f[nt], acc[nt], 0, 0, 0);
  }
#pragma unroll
  for (int nt = 0; nt < 8; nt++) {
#pragma unroll
    for (int r = 0; r < 4; r++) {
      float v = fmaxf(acc[nt][r] + b1r[nt], 0.f);
      unsigned int lo = f2bf(v);
      unsigned int hi = __shfl_xor(lo, 1, 64);
      if ((m & 1) == 0) {
        int rr = rbase + quad * 4 + r;
        *(unsigned int*)&sMid[rr * 136 + nt * 16 + m] = lo | (hi << 16);
      }
    }
  }
  bf16x8 w2f[8];
  float4 b2v[2];
#pragma unroll
  for (int ct = 0; ct < 2; ct++) {
    b2v[ct] = *(const float4*)&b2[w * 32 + ct * 16 + quad * 4];
#pragma unroll
    for (int kb = 0; kb < 4; kb++)
      w2f[ct * 4 + kb] = *(const bf16x8*)(w2t + (size_t)(w * 32 + ct * 16 + m) * 128 + kb * 32 + quad * 8);
  }
  __syncthreads();  // b2: sMid complete

  f32x4 acc2[8];
#pragma unroll
  for (int i = 0; i < 8; i++) acc2[i] = z4;
#pragma unroll
  for (int rt = 0; rt < 4; rt++) {
#pragma unroll
    for (int kb = 0; kb < 4; kb++) {
      bf16x8 a = *(const bf16x8*)(&sMid[(rt * 16 + m) * 136 + kb * 32 + quad * 8]);
      // swapped operands: D^T[ch][edge]
      acc2[rt * 2 + 0] = __builtin_amdgcn_mfma_f32_16x16x32_bf16(w2f[kb], a, acc2[rt * 2 + 0], 0, 0, 0);
      acc2[rt * 2 + 1] = __builtin_amdgcn_mfma_f32_16x16x32_bf16(w2f[4 + kb], a, acc2[rt * 2 + 1], 0, 0, 0);
    }
  }
  // direct epilogue: lane holds edge (rt*16+m), channels w*32+ct*16+quad*4+{0..3}
#pragma unroll
  for (int rt = 0; rt < 4; rt++) {
#pragma unroll
    for (int ct = 0; ct < 2; ct++) {
      f32x4 a4 = acc2[rt * 2 + ct];
      u16 q0 = f2bf(a4[0] + b2v[ct].x);
      u16 q1 = f2bf(a4[1] + b2v[ct].y);
      u16 q2 = f2bf(a4[2] + b2v[ct].z);
      u16 q3 = f2bf(a4[3] + b2v[ct].w);
      uint2 pk;
      pk.x = (unsigned int)q0 | ((unsigned int)q1 << 16);
      pk.y = (unsigned int)q2 | ((unsigned int)q3 << 16);
      *(uint2*)(e_perm + (size_t)(s0 + rt * 16 + m) * 128 + w * 32 + ct * 16 + quad * 4) = pk;
    }
  }
}

// ---------------- aggregate v7: 4 waves/block, one node per wave ------------
// z[n] = bf16( hb[n] + sum_{e->n} relu(hb[src]+e) ).  64-thread workgroups
// capped occupancy at ~16 waves/CU (workgroup slots); 256-thread blocks with
// 4 independent waves lift the cap for this latency-bound gather.
__global__ __launch_bounds__(256) void aggregate_k(const u16* __restrict__ hb,
                                                   const u16* __restrict__ e_perm,
                                                   const int* __restrict__ offs,
                                                   const int* __restrict__ csr_src,
                                                   u16* __restrict__ z, int n) {
  int node = blockIdx.x * 4 + (threadIdx.x >> 6);
  if (node >= n) return;
  int lane = threadIdx.x & 63;
  int q = lane >> 4, li = lane & 15;  // quarter, lane-in-quarter; cols li*8..+7
  int s0 = offs[node], s1 = offs[node + 1];
  float a[8];
#pragma unroll
  for (int j = 0; j < 8; j++) a[j] = 0.f;
  int s = s0 + q;
  for (; s + 8 <= s1; s += 8) {  // edges s and s+4, both valid
    int v0 = csr_src[s], v1 = csr_src[s + 4];
    u16x8 h0 = *(const u16x8*)(hb + (size_t)v0 * 128 + li * 8);
    u16x8 e0 = *(const u16x8*)(e_perm + (size_t)s * 128 + li * 8);
    u16x8 h1 = *(const u16x8*)(hb + (size_t)v1 * 128 + li * 8);
    u16x8 e1 = *(const u16x8*)(e_perm + (size_t)(s + 4) * 128 + li * 8);
#pragma unroll
    for (int j = 0; j < 8; j++) {
      a[j] += fmaxf(bf2f(h0[j]) + bf2f(e0[j]), 0.f);
      a[j] += fmaxf(bf2f(h1[j]) + bf2f(e1[j]), 0.f);
    }
  }
  for (; s < s1; s += 4) {
    int v = csr_src[s];
    u16x8 hv = *(const u16x8*)(hb + (size_t)v * 128 + li * 8);
    u16x8 ev = *(const u16x8*)(e_perm + (size_t)s * 128 + li * 8);
#pragma unroll
    for (int j = 0; j < 8; j++) a[j] += fmaxf(bf2f(hv[j]) + bf2f(ev[j]), 0.f);
  }
#pragma unroll
  for (int j = 0; j < 8; j++) {
    a[j] += __shfl_xor(a[j], 16, 64);
    a[j] += __shfl_xor(a[j], 32, 64);
  }
  if (q == 0) {
    u16x8 hv = *(const u16x8*)(hb + (size_t)node * 128 + li * 8);
    u16x8 o;
#pragma unroll
    for (int j = 0; j < 8; j++) o[j] = f2bf(bf2f(hv[j]) + a[j]);
    *(u16x8*)(z + (size_t)node * 128 + li * 8) = o;
  }
}

// ---------------- conv MLP v3: swapped GEMM2, packed 8B stores --------------
// hb = bf16( relu(BN(relu(z@W1+b1)@W2+b2)) ).
__global__ __launch_bounds__(256) void conv_mlp(const u16* __restrict__ zb,
                                                u16* __restrict__ hb,
                                                const u16* __restrict__ w1t, const u16* __restrict__ w2t,
                                                const float* __restrict__ b1, const float* __restrict__ b2,
                                                const float* __restrict__ gam, const float* __restrict__ bet,
                                                int n) {
  __shared__ alignas(16) u16 sZ[64 * 136];
  __shared__ alignas(16) u16 sMid[64 * 136];
  int t = threadIdx.x;
  int lane = t & 63, w = t >> 6, m = lane & 15, quad = lane >> 4;
  int row0 = blockIdx.x * 64;
#pragma unroll
  for (int i = 0; i < 4; i++) {
    int idx = t + 256 * i; int r = idx >> 4, c = idx & 15;
    int grow = row0 + r; if (grow > n - 1) grow = n - 1;
    *(uint4*)&sZ[r * 136 + c * 8] = *(const uint4*)(zb + (size_t)grow * 128 + c * 8);
  }
  bf16x8 w1f[8];
  float b1r[2];
#pragma unroll
  for (int ct = 0; ct < 2; ct++) {
    b1r[ct] = b1[w * 32 + ct * 16 + m];
#pragma unroll
    for (int kb = 0; kb < 4; kb++)
      w1f[ct * 4 + kb] = *(const bf16x8*)(w1t + (size_t)(w * 32 + ct * 16 + m) * 128 + kb * 32 + quad * 8);
  }
  __syncthreads();  // b1: sZ complete

  f32x4 z4 = {0.f, 0.f, 0.f, 0.f};
  f32x4 acc[8];  // [rt*2+ct]
#pragma unroll
  for (int i = 0; i < 8; i++) acc[i] = z4;
#pragma unroll
  for (int rt = 0; rt < 4; rt++) {
#pragma unroll
    for (int kb = 0; kb < 4; kb++) {
      bf16x8 a = *(const bf16x8*)(&sZ[(rt * 16 + m) * 136 + kb * 32 + quad * 8]);
      acc[rt * 2 + 0] = __builtin_amdgcn_mfma_f32_16x16x32_bf16(a, w1f[kb], acc[rt * 2 + 0], 0, 0, 0);
      acc[rt * 2 + 1] = __builtin_amdgcn_mfma_f32_16x16x32_bf16(a, w1f[4 + kb], acc[rt * 2 + 1], 0, 0, 0);
    }
  }
#pragma unroll
  for (int rt = 0; rt < 4; rt++) {
#pragma unroll
    for (int ct = 0; ct < 2; ct++) {
#pragma unroll
      for (int r = 0; r < 4; r++) {
        float v = fmaxf(acc[rt * 2 + ct][r] + b1r[ct], 0.f);
        unsigned int lo = f2bf(v);
        unsigned int hi = __shfl_xor(lo, 1, 64);
        if ((m & 1) == 0) {
          int rr = rt * 16 + quad * 4 + r;
          int col = w * 32 + ct * 16 + m;
          *(unsigned int*)&sMid[rr * 136 + col] = lo | (hi << 16);
        }
      }
    }
  }
  bf16x8 w2f[8];
  float4 b2v[2], gamv[2], betv[2];
#pragma unroll
  for (int ct = 0; ct < 2; ct++) {
    int c0 = w * 32 + ct * 16 + quad * 4;
    b2v[ct] = *(const float4*)&b2[c0];
    gamv[ct] = *(const float4*)&gam[c0];
    betv[ct] = *(const float4*)&bet[c0];
#pragma unroll
    for (int kb = 0; kb < 4; kb++)
      w2f[ct * 4 + kb] = *(const bf16x8*)(w2t + (size_t)(w * 32 + ct * 16 + m) * 128 + kb * 32 + quad * 8);
  }
  __syncthreads();  // b2: sMid complete

  f32x4 acc2[8];
#pragma unroll
  for (int i = 0; i < 8; i++) acc2[i] = z4;
#pragma unroll
  for (int rt = 0; rt < 4; rt++) {
#pragma unroll
    for (int kb = 0; kb < 4; kb++) {
      bf16x8 a = *(const bf16x8*)(&sMid[(rt * 16 + m) * 136 + kb * 32 + quad * 8]);
      // swapped operands: D^T[ch][node]
      acc2[rt * 2 + 0] = __builtin_amdgcn_mfma_f32_16x16x32_bf16(w2f[kb], a, acc2[rt * 2 + 0], 0, 0, 0);
      acc2[rt * 2 + 1] = __builtin_amdgcn_mfma_f32_16x16x32_bf16(w2f[4 + kb], a, acc2[rt * 2 + 1], 0, 0, 0);
    }
  }
  const float bns = 0.99999500003749983f;  // 1/sqrt(1+1e-5)
#pragma unroll
  for (int rt = 0; rt < 4; rt++) {
    int grow = row0 + rt * 16 + m;
    if (grow < n) {
#pragma unroll
      for (int ct = 0; ct < 2; ct++) {
        f32x4 a4 = acc2[rt * 2 + ct];
        u16 q0 = f2bf(fmaxf((a4[0] + b2v[ct].x) * bns * gamv[ct].x + betv[ct].x, 0.f));
        u16 q1 = f2bf(fmaxf((a4[1] + b2v[ct].y) * bns * gamv[ct].y + betv[ct].y, 0.f));
        u16 q2 = f2bf(fmaxf((a4[2] + b2v[ct].z) * bns * gamv[ct].z + betv[ct].z, 0.f));
        u16 q3 = f2bf(fmaxf((a4[3] + b2v[ct].w) * bns * gamv[ct].w + betv[ct].w, 0.f));
        uint2 pk;
        pk.x = (unsigned int)q0 | ((unsigned int)q1 << 16);
        pk.y = (unsigned int)q2 | ((unsigned int)q3 << 16);
        *(uint2*)(hb + (size_t)grow * 128 + w * 32 + ct * 16 + quad * 4) = pk;
      }
    }
  }
}

// ---------------- gate v2: MFMA 64-node tiles ------------------------------
// gate[n] = relu(hb@W1+b1)@w2 + b2.  W1 pre-transposed to bf16 [64ch][128k].
__global__ __launch_bounds__(256) void gate_k(const u16* __restrict__ hb,
                                              const u16* __restrict__ w1t,
                                              const float* __restrict__ b1,
                                              const float* __restrict__ w2,
                                              const float* __restrict__ b2,
                                              float* __restrict__ gate, int n) {
  __shared__ alignas(16) u16 sA[64 * 136];
  __shared__ alignas(16) u16 sW[64 * 136];
  int t = threadIdx.x;
  int row0 = blockIdx.x * 64;
#pragma unroll
  for (int i = 0; i < 4; i++) {
    int idx = t + 256 * i; int r = idx >> 4, c = idx & 15;
    int grow = row0 + r; if (grow > n - 1) grow = n - 1;
    *(uint4*)&sA[r * 136 + c * 8] = *(const uint4*)(hb + (size_t)grow * 128 + c * 8);
  }
#pragma unroll
  for (int i = 0; i < 4; i++) {
    int idx = t + 256 * i; int r = idx >> 4, c = idx & 15;
    *(uint4*)&sW[r * 136 + c * 8] = *(const uint4*)(w1t + r * 128 + c * 8);
  }
  __syncthreads();
  int lane = t & 63, w = t >> 6, m = lane & 15, quad = lane >> 4, rbase = w * 16;
  f32x4 z4 = {0.f, 0.f, 0.f, 0.f};
  f32x4 acc[4];
#pragma unroll
  for (int i = 0; i < 4; i++) acc[i] = z4;
#pragma unroll
  for (int kb = 0; kb < 4; kb++) {
    bf16x8 a = *(const bf16x8*)(&sA[(rbase + m) * 136 + kb * 32 + quad * 8]);
#pragma unroll
    for (int nt = 0; nt < 4; nt++) {
      bf16x8 b = *(const bf16x8*)(&sW[(nt * 16 + m) * 136 + kb * 32 + quad * 8]);
      acc[nt] = __builtin_amdgcn_mfma_f32_16x16x32_bf16(a, b, acc[nt], 0, 0, 0);
    }
  }
  float b1v[4], w2v[4];
#pragma unroll
  for (int nt = 0; nt < 4; nt++) { b1v[nt] = b1[nt * 16 + m]; w2v[nt] = w2[nt * 16 + m]; }
  float b2v = b2[0];
#pragma unroll
  for (int r = 0; r < 4; r++) {
    float p = 0.f;
#pragma unroll
    for (int nt = 0; nt < 4; nt++) p += fmaxf(acc[nt][r] + b1v[nt], 0.f) * w2v[nt];
    p += __shfl_xor(p, 1, 64);
    p += __shfl_xor(p, 2, 64);
    p += __shfl_xor(p, 4, 64);
    p += __shfl_xor(p, 8, 64);
    if (m == 0) {
      int grow = row0 + rbase + quad * 4 + r;
      if (grow < n) gate[grow] = p + b2v;
    }
  }
}

// ---------------- pooled segment softmax (256 threads, parity-split) --------
__global__ __launch_bounds__(256) void pool_k(const float* __restrict__ gate,
                                              const u16* __restrict__ hb,
                                              const int* __restrict__ goffs,
                                              float* __restrict__ gpool) {
  int g = blockIdx.x, t = threadIdx.x;  // 256 threads
  int s0 = goffs[g], s1 = goffs[g + 1];
  int lane = t & 63, w = t >> 6;
  __shared__ float red[4];
  __shared__ float fin[2][128];
  float mx = -3.4e38f;
  for (int i = s0 + t; i < s1; i += 256) mx = fmaxf(mx, gate[i]);
  for (int d = 32; d; d >>= 1) mx = fmaxf(mx, __shfl_xor(mx, d, 64));
  if (lane == 0) red[w] = mx;
  __syncthreads();
  mx = fmaxf(fmaxf(red[0], red[1]), fmaxf(red[2], red[3]));
  __syncthreads();
  float sm = 0.f;
  for (int i = s0 + t; i < s1; i += 256) sm += __expf(gate[i] - mx);
  for (int d = 32; d; d >>= 1) sm += __shfl_xor(sm, d, 64);
  if (lane == 0) red[w] = sm;
  __syncthreads();
  sm = red[0] + red[1] + red[2] + red[3];
  int g2 = t >> 7, tc = t & 127;
  float acc = 0.f;
  for (int i = s0 + g2; i < s1; i += 2)
    acc += __expf(gate[i] - mx) * bf2f(hb[(size_t)i * 128 + tc]);
  fin[g2][tc] = acc;
  __syncthreads();
  if (t < 128) gpool[g * 128 + t] = (s1 > s0) ? (fin[0][t] + fin[1][t]) / sm : 0.f;
}

// ---------------- head ------------------------------------------------------
__global__ __launch_bounds__(128) void head_k(const float* __restrict__ gpool,
                                              const float* __restrict__ w1, const float* __restrict__ b1,
                                              const float* __restrict__ w2, const float* __restrict__ b2,
                                              float* __restrict__ out) {
  int g = blockIdx.x, t = threadIdx.x;  // 128
  __shared__ float sg[128];
  __shared__ float shid[128];
  sg[t] = gpool[g * 128 + t];
  __syncthreads();
  float s = 0.f;
  for (int k = 0; k < 128; k++) s += sg[k] * w1[k * 128 + t];
  shid[t] = fmaxf(s + b1[t], 0.f);
  __syncthreads();
  if (t < 5) {
    float o = b2[t];
    for (int k = 0; k < 128; k++) o += shid[k] * w2[k * 5 + t];
    out[g * 5 + t] = o;
  }
}

// ---------------- launcher ---------------------------------------------------
extern "C" void kernel_launch(void* const* d_in, const int* in_sizes, int n_in,
                              void* d_out, int out_size, void* d_ws, size_t ws_size,
                              hipStream_t stream) {
  const int N = NNODES, E = NEDGES, G = NGRAPH;
  const float* x = (const float*)d_in[0];
  const float* edge_attr = (const float*)d_in[1];
  const float* node_w = (const float*)d_in[2];
  const float* node_b = (const float*)d_in[3];
  const float* edge_w1 = (const float*)d_in[4];
  const float* edge_b1 = (const float*)d_in[5];
  const float* edge_w2 = (const float*)d_in[6];
  const float* edge_b2 = (const float*)d_in[7];
  const float* conv_w1 = (const float*)d_in[8];
  const float* conv_b1 = (const float*)d_in[9];
  const float* conv_w2 = (const float*)d_in[10];
  const float* conv_b2 = (const float*)d_in[11];
  const float* bn_gamma = (const float*)d_in[12];
  const float* bn_beta = (const float*)d_in[13];
  const float* gate_w1 = (const float*)d_in[14];
  const float* gate_b1 = (const float*)d_in[15];
  const float* gate_w2 = (const float*)d_in[16];
  const float* gate_b2 = (const float*)d_in[17];
  const float* head_w1 = (const float*)d_in[18];
  const float* head_b1 = (const float*)d_in[19];
  const float* head_w2 = (const float*)d_in[20];
  const float* head_b2 = (const float*)d_in[21];
  const int* eidx = (const int*)d_in[22];
  const int* batch = (const int*)d_in[23];
  const int* esrc = eidx;
  const int* edst = eidx + E;

  char* wp = (char*)d_ws;
  auto alloc = [&](size_t bytes) { char* p = wp; wp += (bytes + 255) & ~(size_t)255; return p; };
  u16* e_perm = (u16*)alloc((size_t)E * 128 * 2);
  u16* hb = (u16*)alloc((size_t)(N + 16) * 128 * 2);  // +pad for tile overread
  u16* zb = (u16*)alloc((size_t)N * 128 * 2);
  float* gate = (float*)alloc((size_t)N * 4);
  float* gpool = (float*)alloc((size_t)G * 128 * 4);
  int* counts = (int*)alloc((size_t)N * 4);
  int* offs = (int*)alloc((size_t)(N + 1) * 4);
  int* cursor = (int*)alloc((size_t)N * 4);
  int* csr_src = (int*)alloc((size_t)E * 4);
  int* csr_eid = (int*)alloc((size_t)E * 4);
  int* bsums = (int*)alloc(64 * 4);
  int* gcounts = (int*)alloc(G * 4);
  int* goffs = (int*)alloc((G + 1) * 4);
  u16* node_wt = (u16*)alloc(8192 * 2);
  u16* edge_w1t = (u16*)alloc(4096 * 2);
  u16* edge_w2t = (u16*)alloc(16384 * 2);
  u16* conv_w1t = (u16*)alloc(65536 * 2);
  u16* conv_w2t = (u16*)alloc(65536 * 2);
  u16* gate_w1t = (u16*)alloc(8192 * 2);

  size_t need = (size_t)(wp - (char*)d_ws);
  if (need > ws_size) {
    write_zero_f32<<<(out_size + 255) / 256, 256, 0, stream>>>((float*)d_out, out_size);
    return;
  }

  zero_counts<<<(N + 255) / 256, 256, 0, stream>>>(counts, N, gcounts, G);
  prep_weights<<<656, 256, 0, stream>>>(node_w, edge_w1, edge_w2, conv_w1, conv_w2, gate_w1,
                                        node_wt, edge_w1t, edge_w2t, conv_w1t, conv_w2t, gate_w1t);
  hist_all<<<E / 256, 256, 0, stream>>>(edst, batch, counts, gcounts, N);
  scan_a<<<49, 256, 0, stream>>>(counts, bsums, N);
  scan_b<<<1, 64, 0, stream>>>(bsums, offs, 49, N);
  scan_c<<<49, 256, 0, stream>>>(counts, bsums, offs, cursor, N);
  gscan<<<1, 256, 0, stream>>>(gcounts, goffs);
  scatter_csr<<<E / 256, 256, 0, stream>>>(esrc, edst, cursor, csr_src, csr_eid);
  node_encode<<<(N + 63) / 64, 256, 0, stream>>>(x, node_wt, node_b, hb, N);
  edge_encode<<<E / 64, 256, 0, stream>>>(edge_attr, edge_w1t, edge_w2t, edge_b1, edge_b2,
                                          csr_eid, e_perm);
  for (int l = 0; l < 4; l++) {
    aggregate_k<<<(N + 3) / 4, 256, 0, stream>>>(hb, e_perm, offs, csr_src, zb, N);
    conv_mlp<<<(N + 63) / 64, 256, 0, stream>>>(zb, hb, conv_w1t + l * 16384, conv_w2t + l * 16384,
                                                conv_b1 + l * 128, conv_b2 + l * 128,
                                                bn_gamma + l * 128, bn_beta + l * 128, N);
  }
  gate_k<<<(N + 63) / 64, 256, 0, stream>>>(hb, gate_w1t, gate_b1, gate_w2, gate_b2, gate, N);
  pool_k<<<G, 256, 0, stream>>>(gate, hb, goffs, gpool);
  head_k<<<G, 128, 0, stream>>>(gpool, head_w1, head_b1, head_w2, head_b2, (float*)d_out);
}

// Round 2
// 655.207 us; speedup vs baseline: 1.0796x; 1.0498x over previous
//
#include <hip/hip_runtime.h>

typedef unsigned short u16;
typedef __bf16 bf16x8 __attribute__((ext_vector_type(8)));
typedef float f32x4 __attribute__((ext_vector_type(4)));
typedef unsigned short u16x8 __attribute__((ext_vector_type(8)));

#define NNODES 50000
#define NEDGES 640000
#define NGRAPH 256

__device__ __forceinline__ float bf2f(u16 u) {
  unsigned int v = ((unsigned int)u) << 16; float f; __builtin_memcpy(&f, &v, 4); return f;
}
__device__ __forceinline__ u16 f2bf(float f) {
  unsigned int x; __builtin_memcpy(&x, &f, 4);
  unsigned int lsb = (x >> 16) & 1u;
  x += 0x7fffu + lsb;
  return (u16)(x >> 16);
}

// ---------------- safe fallback: zero fp32 output ---------------------------
__global__ void write_zero_f32(float* __restrict__ out, int n) {
  int i = blockIdx.x * 256 + threadIdx.x;
  if (i < n) out[i] = 0.f;
}

// ---------------- zero-init scratch counters --------------------------------
__global__ void zero_counts(int* __restrict__ a, int na, int* __restrict__ b, int nb) {
  int i = blockIdx.x * 256 + threadIdx.x;
  if (i < na) a[i] = 0;
  if (i < nb) b[i] = 0;
}

// ---------------- weight prep: fp32 -> bf16 transpose (B-layout Wt[n][k]) ---
__global__ void prep_weights(const float* __restrict__ node_w, const float* __restrict__ edge_w1,
                             const float* __restrict__ edge_w2, const float* __restrict__ conv_w1,
                             const float* __restrict__ conv_w2, const float* __restrict__ gate_w1,
                             u16* __restrict__ node_wt, u16* __restrict__ edge_w1t,
                             u16* __restrict__ edge_w2t, u16* __restrict__ conv_w1t,
                             u16* __restrict__ conv_w2t, u16* __restrict__ gate_w1t) {
  int o = blockIdx.x * 256 + threadIdx.x;
  if (o < 8192) { int n = o >> 6, k = o & 63; node_wt[o] = f2bf(node_w[k * 128 + n]); return; }
  o -= 8192;
  if (o < 4096) { int n = o >> 5, k = o & 31;
                  edge_w1t[o] = (k < 16) ? f2bf(edge_w1[k * 128 + n]) : (u16)0; return; }
  o -= 4096;
  if (o < 16384) { int n = o >> 7, k = o & 127; edge_w2t[o] = f2bf(edge_w2[k * 128 + n]); return; }
  o -= 16384;
  if (o < 65536) { int l = o >> 14, r = o & 16383, n = r >> 7, k = r & 127;
                   conv_w1t[o] = f2bf(conv_w1[l * 16384 + k * 128 + n]); return; }
  o -= 65536;
  if (o < 65536) { int l = o >> 14, r = o & 16383, n = r >> 7, k = r & 127;
                   conv_w2t[o] = f2bf(conv_w2[l * 16384 + k * 128 + n]); return; }
  o -= 65536;
  if (o < 8192) { int n = o >> 7, k = o & 127; gate_w1t[o] = f2bf(gate_w1[k * 64 + n]); }
}

// ---------------- CSR build --------------------------------------------------
__global__ void hist_all(const int* __restrict__ dst, const int* __restrict__ b,
                         int* __restrict__ counts, int* __restrict__ gc, int n) {
  int i = blockIdx.x * 256 + threadIdx.x;
  atomicAdd(&counts[dst[i]], 1);
  if (i < n) atomicAdd(&gc[b[i]], 1);
}
__global__ void scan_a(const int* __restrict__ counts, int* __restrict__ bsums, int n) {
  int b = blockIdx.x, t = threadIdx.x;
  int i0 = b * 1024 + t * 4;
  int s = 0;
#pragma unroll
  for (int j = 0; j < 4; j++) { int i = i0 + j; if (i < n) s += counts[i]; }
  int lane = t & 63, w = t >> 6;
  for (int m = 32; m; m >>= 1) s += __shfl_xor(s, m, 64);
  __shared__ int ws_[4];
  if (lane == 0) ws_[w] = s;
  __syncthreads();
  if (t == 0) bsums[b] = ws_[0] + ws_[1] + ws_[2] + ws_[3];
}
__global__ void scan_b(int* __restrict__ bsums, int* __restrict__ offs, int nb, int n) {
  if (threadIdx.x == 0) {
    int run = 0;
    for (int i = 0; i < nb; i++) { int v = bsums[i]; bsums[i] = run; run += v; }
    offs[n] = run;
  }
}
__global__ void scan_c(const int* __restrict__ counts, const int* __restrict__ boffs,
                       int* __restrict__ offs, int* __restrict__ cursor, int n) {
  int b = blockIdx.x, t = threadIdx.x;
  int i0 = b * 1024 + t * 4;
  int v[4]; int s = 0;
#pragma unroll
  for (int j = 0; j < 4; j++) { v[j] = (i0 + j < n) ? counts[i0 + j] : 0; s += v[j]; }
  int lane = t & 63, w = t >> 6;
  int x = s;
  for (int d = 1; d < 64; d <<= 1) { int y = __shfl_up(x, (unsigned)d, 64); if (lane >= d) x += y; }
  __shared__ int wt_[4];
  if (lane == 63) wt_[w] = x;
  __syncthreads();
  int add = boffs[b];
  for (int i = 0; i < w; i++) add += wt_[i];
  int excl = add + x - s;
#pragma unroll
  for (int j = 0; j < 4; j++) {
    int i = i0 + j;
    if (i < n) { offs[i] = excl; cursor[i] = excl; }
    excl += v[j];
  }
}
__global__ void gscan(const int* __restrict__ gcounts, int* __restrict__ goffs) {
  int t = threadIdx.x;  // 256
  int v = gcounts[t];
  int lane = t & 63, w = t >> 6;
  int x = v;
  for (int d = 1; d < 64; d <<= 1) { int y = __shfl_up(x, (unsigned)d, 64); if (lane >= d) x += y; }
  __shared__ int wt_[4];
  if (lane == 63) wt_[w] = x;
  __syncthreads();
  int add = 0;
  for (int i = 0; i < w; i++) add += wt_[i];
  int incl = add + x;
  goffs[t] = incl - v;
  if (t == 255) goffs[256] = incl;
}
__global__ void scatter_csr(const int* __restrict__ src, const int* __restrict__ dst,
                            int* __restrict__ cursor, int* __restrict__ csr_src,
                            int* __restrict__ csr_eid) {
  int i = blockIdx.x * 256 + threadIdx.x;
  int d = dst[i];
  int p = atomicAdd(&cursor[d], 1);
  csr_src[p] = src[i];
  csr_eid[p] = i;
}

// ---------------- MFMA tile helper (A,B both from LDS) ----------------------
template <int KB, int SA, int SB>
__device__ __forceinline__ void mfma_block(const u16* aL, const u16* bL, int m, int quad,
                                           int rbase, f32x4* acc) {
#pragma unroll
  for (int kb = 0; kb < KB; ++kb) {
    bf16x8 a = *(const bf16x8*)(aL + (rbase + m) * SA + kb * 32 + quad * 8);
#pragma unroll
    for (int nt = 0; nt < 8; ++nt) {
      bf16x8 b = *(const bf16x8*)(bL + (nt * 16 + m) * SB + kb * 32 + quad * 8);
      acc[nt] = __builtin_amdgcn_mfma_f32_16x16x32_bf16(a, b, acc[nt], 0, 0, 0);
    }
  }
}

// ---------------- node encoder: hb = bf16(x @ node_w + node_b) --------------
__global__ __launch_bounds__(256) void node_encode(const float* __restrict__ x,
                                                   const u16* __restrict__ wt,
                                                   const float* __restrict__ nb,
                                                   u16* __restrict__ hb, int n) {
  __shared__ alignas(16) u16 sA[64 * 72];
  __shared__ alignas(16) u16 sW[128 * 72];
  int t = threadIdx.x;
  int row0 = blockIdx.x * 64;
#pragma unroll
  for (int i = 0; i < 4; i++) {
    int idx = t + 256 * i; int r = idx >> 4, c = idx & 15;  // 64 rows x 16 float4 (K=64)
    int grow = row0 + r; if (grow > n - 1) grow = n - 1;
    float4 v = *(const float4*)(x + (size_t)grow * 64 + c * 4);
    ushort4 o; o.x = f2bf(v.x); o.y = f2bf(v.y); o.z = f2bf(v.z); o.w = f2bf(v.w);
    *(ushort4*)&sA[r * 72 + c * 4] = o;
  }
#pragma unroll
  for (int i = 0; i < 4; i++) {
    int idx = t + 256 * i; int nr = idx >> 3, c = idx & 7;  // 128 rows x 8 uint4 (K=64)
    *(uint4*)&sW[nr * 72 + c * 8] = *(const uint4*)(wt + nr * 64 + c * 8);
  }
  __syncthreads();
  int lane = t & 63, w = t >> 6, m = lane & 15, quad = lane >> 4, rbase = w * 16;
  f32x4 acc[8];
  f32x4 z4 = {0.f, 0.f, 0.f, 0.f};
#pragma unroll
  for (int i = 0; i < 8; i++) acc[i] = z4;
  mfma_block<2, 72, 72>(sA, sW, m, quad, rbase, acc);
#pragma unroll
  for (int nt = 0; nt < 8; nt++) {
    int col = nt * 16 + m;
    float bb = nb[col];
    f32x4 a4 = acc[nt];
#pragma unroll
    for (int r = 0; r < 4; r++) {
      int grow = row0 + rbase + quad * 4 + r;
      if (grow < n) hb[(size_t)grow * 128 + col] = f2bf(a4[r] + bb);
    }
  }
}

// ---------------- edge encoder v9: both GEMMs swapped, LDS pack, coalesced --
// GEMM1 and GEMM2 computed as D^T (weights as first MFMA operand): lane holds
// 4 consecutive channels of one edge -> uint2 LDS pack (no shfl, no
// divergence), then fully-coalesced 16B/lane global copy-out (v8's direct
// scattered global stores regressed 99->114us).
__global__ __launch_bounds__(256) void edge_encode(const float* __restrict__ ea,
                                                   const u16* __restrict__ w1t,
                                                   const u16* __restrict__ w2t,
                                                   const float* __restrict__ b1,
                                                   const float* __restrict__ b2,
                                                   const int* __restrict__ csr_eid,
                                                   u16* __restrict__ e_perm) {
  __shared__ alignas(16) u16 sA[64 * 48];     // K padded 16->32
  __shared__ alignas(16) u16 sMid[64 * 136];  // GEMM1 out / GEMM2 in / out tile
  int t = threadIdx.x;
  int lane = t & 63, w = t >> 6, m = lane & 15, quad = lane >> 4, rbase = w * 16;
  int s0 = blockIdx.x * 64;

  if (t < 128) {
    int r = t >> 1, c = t & 1;
    uint4 z = {0, 0, 0, 0};
    *(uint4*)&sA[r * 48 + 16 + c * 8] = z;
  }
  {
    int eidv = 0;
    if (lane < 16) eidv = csr_eid[s0 + w * 16 + lane];
    int r = lane >> 2, c = lane & 3;
    int eid = __shfl(eidv, r, 64);
    float4 v = *(const float4*)(ea + (size_t)eid * 16 + c * 4);
    ushort4 o; o.x = f2bf(v.x); o.y = f2bf(v.y); o.z = f2bf(v.z); o.w = f2bf(v.w);
    *(ushort4*)&sA[(w * 16 + r) * 48 + c * 4] = o;
  }
  bf16x8 w1f[8];
#pragma unroll
  for (int nt = 0; nt < 8; nt++)
    w1f[nt] = *(const bf16x8*)(w1t + (nt * 16 + m) * 32 + quad * 8);
  __syncthreads();  // b1: sA complete

  f32x4 z4 = {0.f, 0.f, 0.f, 0.f};
  f32x4 acc[8];
#pragma unroll
  for (int i = 0; i < 8; i++) acc[i] = z4;
  {
    bf16x8 a = *(const bf16x8*)(&sA[(rbase + m) * 48 + quad * 8]);
#pragma unroll
    for (int nt = 0; nt < 8; nt++)
      acc[nt] = __builtin_amdgcn_mfma_f32_16x16x32_bf16(w1f[nt], a, acc[nt], 0, 0, 0);
  }
  // lane holds ch nt*16+quad*4+r, edge rbase+m -> direct uint2 LDS pack
#pragma unroll
  for (int nt = 0; nt < 8; nt++) {
    float4 bb = *(const float4*)&b1[nt * 16 + quad * 4];
    u16 q0 = f2bf(fmaxf(acc[nt][0] + bb.x, 0.f));
    u16 q1 = f2bf(fmaxf(acc[nt][1] + bb.y, 0.f));
    u16 q2 = f2bf(fmaxf(acc[nt][2] + bb.z, 0.f));
    u16 q3 = f2bf(fmaxf(acc[nt][3] + bb.w, 0.f));
    uint2 pk;
    pk.x = (unsigned int)q0 | ((unsigned int)q1 << 16);
    pk.y = (unsigned int)q2 | ((unsigned int)q3 << 16);
    *(uint2*)&sMid[(rbase + m) * 136 + nt * 16 + quad * 4] = pk;
  }
  bf16x8 w2f[8];
  float4 b2v[2];
#pragma unroll
  for (int ct = 0; ct < 2; ct++) {
    b2v[ct] = *(const float4*)&b2[w * 32 + ct * 16 + quad * 4];
#pragma unroll
    for (int kb = 0; kb < 4; kb++)
      w2f[ct * 4 + kb] = *(const bf16x8*)(w2t + (size_t)(w * 32 + ct * 16 + m) * 128 + kb * 32 + quad * 8);
  }
  __syncthreads();  // b2: sMid complete

  f32x4 acc2[8];
#pragma unroll
  for (int i = 0; i < 8; i++) acc2[i] = z4;
#pragma unroll
  for (int rt = 0; rt < 4; rt++) {
#pragma unroll
    for (int kb = 0; kb < 4; kb++) {
      bf16x8 a = *(const bf16x8*)(&sMid[(rt * 16 + m) * 136 + kb * 32 + quad * 8]);
      acc2[rt * 2 + 0] = __builtin_amdgcn_mfma_f32_16x16x32_bf16(w2f[kb], a, acc2[rt * 2 + 0], 0, 0, 0);
      acc2[rt * 2 + 1] = __builtin_amdgcn_mfma_f32_16x16x32_bf16(w2f[4 + kb], a, acc2[rt * 2 + 1], 0, 0, 0);
    }
  }
  __syncthreads();  // b3: all sMid reads done -> reuse as output tile
#pragma unroll
  for (int rt = 0; rt < 4; rt++) {
#pragma unroll
    for (int ct = 0; ct < 2; ct++) {
      f32x4 a4 = acc2[rt * 2 + ct];
      u16 q0 = f2bf(a4[0] + b2v[ct].x);
      u16 q1 = f2bf(a4[1] + b2v[ct].y);
      u16 q2 = f2bf(a4[2] + b2v[ct].z);
      u16 q3 = f2bf(a4[3] + b2v[ct].w);
      uint2 pk;
      pk.x = (unsigned int)q0 | ((unsigned int)q1 << 16);
      pk.y = (unsigned int)q2 | ((unsigned int)q3 << 16);
      *(uint2*)&sMid[(rt * 16 + m) * 136 + w * 32 + ct * 16 + quad * 4] = pk;
    }
  }
  __syncthreads();  // b4: out tile ready
#pragma unroll
  for (int i = 0; i < 4; i++) {
    int idx = t + 256 * i; int r = idx >> 4, c = idx & 15;
    *(uint4*)(e_perm + (size_t)(s0 + r) * 128 + c * 8) = *(const uint4*)&sMid[r * 136 + c * 8];
  }
}

// ---------------- fused layer: aggregate + conv MLP -------------------------
// Block = 64 nodes.  Phase A: each quarter-wave (16 lanes x 8 ch = 128 ch)
// owns 4 nodes sequentially, aggregates relu(h[src]+e) + h straight into sZ
// (LDS) -> no zb round-trip, no kernel boundary.  Phase B: conv MLP with
// swapped GEMMs and LDS packs; final pack reuses sZ (GEMM1's reads of sZ are
// complete before b2).  hin/hout ping-pong keeps the cross-block h gather
// race-free.
__global__ __launch_bounds__(256) void layer_k(const u16* __restrict__ hin,
                                               u16* __restrict__ hout,
                                               const u16* __restrict__ e_perm,
                                               const int* __restrict__ offs,
                                               const int* __restrict__ csr_src,
                                               const u16* __restrict__ w1t, const u16* __restrict__ w2t,
                                               const float* __restrict__ b1, const float* __restrict__ b2,
                                               const float* __restrict__ gam, const float* __restrict__ bet,
                                               int n) {
  __shared__ alignas(16) u16 sZ[64 * 136];
  __shared__ alignas(16) u16 sMid[64 * 136];
  int t = threadIdx.x;
  int lane = t & 63, w = t >> 6, m = lane & 15, quad = lane >> 4;
  int row0 = blockIdx.x * 64;
  int li = m;               // lane-in-quarter: cols li*8..+7
  int qq = w * 4 + quad;    // quarter id 0..15; nodes qq*4..+3

  // ---- phase A: aggregate 4 nodes per quarter-wave ----
  for (int k = 0; k < 4; k++) {
    int lr = qq * 4 + k;
    int nd = row0 + lr; if (nd > n - 1) nd = n - 1;
    int s0 = offs[nd], s1 = offs[nd + 1];
    float a[8];
#pragma unroll
    for (int j = 0; j < 8; j++) a[j] = 0.f;
    int s = s0;
    for (; s + 2 <= s1; s += 2) {
      int v0 = csr_src[s], v1 = csr_src[s + 1];
      u16x8 h0 = *(const u16x8*)(hin + (size_t)v0 * 128 + li * 8);
      u16x8 e0 = *(const u16x8*)(e_perm + (size_t)s * 128 + li * 8);
      u16x8 h1 = *(const u16x8*)(hin + (size_t)v1 * 128 + li * 8);
      u16x8 e1 = *(const u16x8*)(e_perm + (size_t)(s + 1) * 128 + li * 8);
#pragma unroll
      for (int j = 0; j < 8; j++) {
        a[j] += fmaxf(bf2f(h0[j]) + bf2f(e0[j]), 0.f);
        a[j] += fmaxf(bf2f(h1[j]) + bf2f(e1[j]), 0.f);
      }
    }
    if (s < s1) {
      int v = csr_src[s];
      u16x8 hv = *(const u16x8*)(hin + (size_t)v * 128 + li * 8);
      u16x8 ev = *(const u16x8*)(e_perm + (size_t)s * 128 + li * 8);
#pragma unroll
      for (int j = 0; j < 8; j++) a[j] += fmaxf(bf2f(hv[j]) + bf2f(ev[j]), 0.f);
    }
    u16x8 hv = *(const u16x8*)(hin + (size_t)nd * 128 + li * 8);
    u16x8 o;
#pragma unroll
    for (int j = 0; j < 8; j++) o[j] = f2bf(bf2f(hv[j]) + a[j]);
    *(u16x8*)&sZ[lr * 136 + li * 8] = o;
  }
  // preload W1 fragments + bias while other waves finish aggregating
  bf16x8 w1f[8];
  float4 b1v[2];
#pragma unroll
  for (int ct = 0; ct < 2; ct++) {
    b1v[ct] = *(const float4*)&b1[w * 32 + ct * 16 + quad * 4];
#pragma unroll
    for (int kb = 0; kb < 4; kb++)
      w1f[ct * 4 + kb] = *(const bf16x8*)(w1t + (size_t)(w * 32 + ct * 16 + m) * 128 + kb * 32 + quad * 8);
  }
  __syncthreads();  // bA: sZ complete

  // ---- phase B: conv MLP (both GEMMs swapped -> D^T, LDS packs) ----
  f32x4 z4 = {0.f, 0.f, 0.f, 0.f};
  f32x4 acc[8];
#pragma unroll
  for (int i = 0; i < 8; i++) acc[i] = z4;
#pragma unroll
  for (int rt = 0; rt < 4; rt++) {
#pragma unroll
    for (int kb = 0; kb < 4; kb++) {
      bf16x8 a = *(const bf16x8*)(&sZ[(rt * 16 + m) * 136 + kb * 32 + quad * 8]);
      acc[rt * 2 + 0] = __builtin_amdgcn_mfma_f32_16x16x32_bf16(w1f[kb], a, acc[rt * 2 + 0], 0, 0, 0);
      acc[rt * 2 + 1] = __builtin_amdgcn_mfma_f32_16x16x32_bf16(w1f[4 + kb], a, acc[rt * 2 + 1], 0, 0, 0);
    }
  }
  // lane holds ch w*32+ct*16+quad*4+r, node rt*16+m
#pragma unroll
  for (int rt = 0; rt < 4; rt++) {
#pragma unroll
    for (int ct = 0; ct < 2; ct++) {
      f32x4 a4 = acc[rt * 2 + ct];
      u16 q0 = f2bf(fmaxf(a4[0] + b1v[ct].x, 0.f));
      u16 q1 = f2bf(fmaxf(a4[1] + b1v[ct].y, 0.f));
      u16 q2 = f2bf(fmaxf(a4[2] + b1v[ct].z, 0.f));
      u16 q3 = f2bf(fmaxf(a4[3] + b1v[ct].w, 0.f));
      uint2 pk;
      pk.x = (unsigned int)q0 | ((unsigned int)q1 << 16);
      pk.y = (unsigned int)q2 | ((unsigned int)q3 << 16);
      *(uint2*)&sMid[(rt * 16 + m) * 136 + w * 32 + ct * 16 + quad * 4] = pk;
    }
  }
  bf16x8 w2f[8];
  float4 b2v[2], gamv[2], betv[2];
#pragma unroll
  for (int ct = 0; ct < 2; ct++) {
    int c0 = w * 32 + ct * 16 + quad * 4;
    b2v[ct] = *(const float4*)&b2[c0];
    gamv[ct] = *(const float4*)&gam[c0];
    betv[ct] = *(const float4*)&bet[c0];
#pragma unroll
    for (int kb = 0; kb < 4; kb++)
      w2f[ct * 4 + kb] = *(const bf16x8*)(w2t + (size_t)(w * 32 + ct * 16 + m) * 128 + kb * 32 + quad * 8);
  }
  __syncthreads();  // b2: sMid complete (sZ reads also all done)

  f32x4 acc2[8];
#pragma unroll
  for (int i = 0; i < 8; i++) acc2[i] = z4;
#pragma unroll
  for (int rt = 0; rt < 4; rt++) {
#pragma unroll
    for (int kb = 0; kb < 4; kb++) {
      bf16x8 a = *(const bf16x8*)(&sMid[(rt * 16 + m) * 136 + kb * 32 + quad * 8]);
      acc2[rt * 2 + 0] = __builtin_amdgcn_mfma_f32_16x16x32_bf16(w2f[kb], a, acc2[rt * 2 + 0], 0, 0, 0);
      acc2[rt * 2 + 1] = __builtin_amdgcn_mfma_f32_16x16x32_bf16(w2f[4 + kb], a, acc2[rt * 2 + 1], 0, 0, 0);
    }
  }
  const float bns = 0.99999500003749983f;  // 1/sqrt(1+1e-5)
  // final pack reuses sZ (its readers finished before b2)
#pragma unroll
  for (int rt = 0; rt < 4; rt++) {
#pragma unroll
    for (int ct = 0; ct < 2; ct++) {
      f32x4 a4 = acc2[rt * 2 + ct];
      u16 q0 = f2bf(fmaxf((a4[0] + b2v[ct].x) * bns * gamv[ct].x + betv[ct].x, 0.f));
      u16 q1 = f2bf(fmaxf((a4[1] + b2v[ct].y) * bns * gamv[ct].y + betv[ct].y, 0.f));
      u16 q2 = f2bf(fmaxf((a4[2] + b2v[ct].z) * bns * gamv[ct].z + betv[ct].z, 0.f));
      u16 q3 = f2bf(fmaxf((a4[3] + b2v[ct].w) * bns * gamv[ct].w + betv[ct].w, 0.f));
      uint2 pk;
      pk.x = (unsigned int)q0 | ((unsigned int)q1 << 16);
      pk.y = (unsigned int)q2 | ((unsigned int)q3 << 16);
      *(uint2*)&sZ[(rt * 16 + m) * 136 + w * 32 + ct * 16 + quad * 4] = pk;
    }
  }
  __syncthreads();  // b3: out tile ready
#pragma unroll
  for (int i = 0; i < 4; i++) {
    int idx = t + 256 * i; int r = idx >> 4, c = idx & 15;
    int grow = row0 + r;
    if (grow < n)
      *(uint4*)(hout + (size_t)grow * 128 + c * 8) = *(const uint4*)&sZ[r * 136 + c * 8];
  }
}

// ---------------- gate v2: MFMA 64-node tiles ------------------------------
__global__ __launch_bounds__(256) void gate_k(const u16* __restrict__ hb,
                                              const u16* __restrict__ w1t,
                                              const float* __restrict__ b1,
                                              const float* __restrict__ w2,
                                              const float* __restrict__ b2,
                                              float* __restrict__ gate, int n) {
  __shared__ alignas(16) u16 sA[64 * 136];
  __shared__ alignas(16) u16 sW[64 * 136];
  int t = threadIdx.x;
  int row0 = blockIdx.x * 64;
#pragma unroll
  for (int i = 0; i < 4; i++) {
    int idx = t + 256 * i; int r = idx >> 4, c = idx & 15;
    int grow = row0 + r; if (grow > n - 1) grow = n - 1;
    *(uint4*)&sA[r * 136 + c * 8] = *(const uint4*)(hb + (size_t)grow * 128 + c * 8);
  }
#pragma unroll
  for (int i = 0; i < 4; i++) {
    int idx = t + 256 * i; int r = idx >> 4, c = idx & 15;
    *(uint4*)&sW[r * 136 + c * 8] = *(const uint4*)(w1t + r * 128 + c * 8);
  }
  __syncthreads();
  int lane = t & 63, w = t >> 6, m = lane & 15, quad = lane >> 4, rbase = w * 16;
  f32x4 z4 = {0.f, 0.f, 0.f, 0.f};
  f32x4 acc[4];
#pragma unroll
  for (int i = 0; i < 4; i++) acc[i] = z4;
#pragma unroll
  for (int kb = 0; kb < 4; kb++) {
    bf16x8 a = *(const bf16x8*)(&sA[(rbase + m) * 136 + kb * 32 + quad * 8]);
#pragma unroll
    for (int nt = 0; nt < 4; nt++) {
      bf16x8 b = *(const bf16x8*)(&sW[(nt * 16 + m) * 136 + kb * 32 + quad * 8]);
      acc[nt] = __builtin_amdgcn_mfma_f32_16x16x32_bf16(a, b, acc[nt], 0, 0, 0);
    }
  }
  float b1v[4], w2v[4];
#pragma unroll
  for (int nt = 0; nt < 4; nt++) { b1v[nt] = b1[nt * 16 + m]; w2v[nt] = w2[nt * 16 + m]; }
  float b2v = b2[0];
#pragma unroll
  for (int r = 0; r < 4; r++) {
    float p = 0.f;
#pragma unroll
    for (int nt = 0; nt < 4; nt++) p += fmaxf(acc[nt][r] + b1v[nt], 0.f) * w2v[nt];
    p += __shfl_xor(p, 1, 64);
    p += __shfl_xor(p, 2, 64);
    p += __shfl_xor(p, 4, 64);
    p += __shfl_xor(p, 8, 64);
    if (m == 0) {
      int grow = row0 + rbase + quad * 4 + r;
      if (grow < n) gate[grow] = p + b2v;
    }
  }
}

// ---------------- pooled segment softmax (256 threads, parity-split) --------
__global__ __launch_bounds__(256) void pool_k(const float* __restrict__ gate,
                                              const u16* __restrict__ hb,
                                              const int* __restrict__ goffs,
                                              float* __restrict__ gpool) {
  int g = blockIdx.x, t = threadIdx.x;  // 256 threads
  int s0 = goffs[g], s1 = goffs[g + 1];
  int lane = t & 63, w = t >> 6;
  __shared__ float red[4];
  __shared__ float fin[2][128];
  float mx = -3.4e38f;
  for (int i = s0 + t; i < s1; i += 256) mx = fmaxf(mx, gate[i]);
  for (int d = 32; d; d >>= 1) mx = fmaxf(mx, __shfl_xor(mx, d, 64));
  if (lane == 0) red[w] = mx;
  __syncthreads();
  mx = fmaxf(fmaxf(red[0], red[1]), fmaxf(red[2], red[3]));
  __syncthreads();
  float sm = 0.f;
  for (int i = s0 + t; i < s1; i += 256) sm += __expf(gate[i] - mx);
  for (int d = 32; d; d >>= 1) sm += __shfl_xor(sm, d, 64);
  if (lane == 0) red[w] = sm;
  __syncthreads();
  sm = red[0] + red[1] + red[2] + red[3];
  int g2 = t >> 7, tc = t & 127;
  float acc = 0.f;
  for (int i = s0 + g2; i < s1; i += 2)
    acc += __expf(gate[i] - mx) * bf2f(hb[(size_t)i * 128 + tc]);
  fin[g2][tc] = acc;
  __syncthreads();
  if (t < 128) gpool[g * 128 + t] = (s1 > s0) ? (fin[0][t] + fin[1][t]) / sm : 0.f;
}

// ---------------- head ------------------------------------------------------
__global__ __launch_bounds__(128) void head_k(const float* __restrict__ gpool,
                                              const float* __restrict__ w1, const float* __restrict__ b1,
                                              const float* __restrict__ w2, const float* __restrict__ b2,
                                              float* __restrict__ out) {
  int g = blockIdx.x, t = threadIdx.x;  // 128
  __shared__ float sg[128];
  __shared__ float shid[128];
  sg[t] = gpool[g * 128 + t];
  __syncthreads();
  float s = 0.f;
  for (int k = 0; k < 128; k++) s += sg[k] * w1[k * 128 + t];
  shid[t] = fmaxf(s + b1[t], 0.f);
  __syncthreads();
  if (t < 5) {
    float o = b2[t];
    for (int k = 0; k < 128; k++) o += shid[k] * w2[k * 5 + t];
    out[g * 5 + t] = o;
  }
}

// ---------------- launcher ---------------------------------------------------
extern "C" void kernel_launch(void* const* d_in, const int* in_sizes, int n_in,
                              void* d_out, int out_size, void* d_ws, size_t ws_size,
                              hipStream_t stream) {
  const int N = NNODES, E = NEDGES, G = NGRAPH;
  const float* x = (const float*)d_in[0];
  const float* edge_attr = (const float*)d_in[1];
  const float* node_w = (const float*)d_in[2];
  const float* node_b = (const float*)d_in[3];
  const float* edge_w1 = (const float*)d_in[4];
  const float* edge_b1 = (const float*)d_in[5];
  const float* edge_w2 = (const float*)d_in[6];
  const float* edge_b2 = (const float*)d_in[7];
  const float* conv_w1 = (const float*)d_in[8];
  const float* conv_b1 = (const float*)d_in[9];
  const float* conv_w2 = (const float*)d_in[10];
  const float* conv_b2 = (const float*)d_in[11];
  const float* bn_gamma = (const float*)d_in[12];
  const float* bn_beta = (const float*)d_in[13];
  const float* gate_w1 = (const float*)d_in[14];
  const float* gate_b1 = (const float*)d_in[15];
  const float* gate_w2 = (const float*)d_in[16];
  const float* gate_b2 = (const float*)d_in[17];
  const float* head_w1 = (const float*)d_in[18];
  const float* head_b1 = (const float*)d_in[19];
  const float* head_w2 = (const float*)d_in[20];
  const float* head_b2 = (const float*)d_in[21];
  const int* eidx = (const int*)d_in[22];
  const int* batch = (const int*)d_in[23];
  const int* esrc = eidx;
  const int* edst = eidx + E;

  char* wp = (char*)d_ws;
  auto alloc = [&](size_t bytes) { char* p = wp; wp += (bytes + 255) & ~(size_t)255; return p; };
  u16* e_perm = (u16*)alloc((size_t)E * 128 * 2);
  u16* hb = (u16*)alloc((size_t)(N + 16) * 128 * 2);   // +pad for tile overread
  u16* hb2 = (u16*)alloc((size_t)(N + 16) * 128 * 2);  // ping-pong partner
  float* gate = (float*)alloc((size_t)N * 4);
  float* gpool = (float*)alloc((size_t)G * 128 * 4);
  int* counts = (int*)alloc((size_t)N * 4);
  int* offs = (int*)alloc((size_t)(N + 1) * 4);
  int* cursor = (int*)alloc((size_t)N * 4);
  int* csr_src = (int*)alloc((size_t)E * 4);
  int* csr_eid = (int*)alloc((size_t)E * 4);
  int* bsums = (int*)alloc(64 * 4);
  int* gcounts = (int*)alloc(G * 4);
  int* goffs = (int*)alloc((G + 1) * 4);
  u16* node_wt = (u16*)alloc(8192 * 2);
  u16* edge_w1t = (u16*)alloc(4096 * 2);
  u16* edge_w2t = (u16*)alloc(16384 * 2);
  u16* conv_w1t = (u16*)alloc(65536 * 2);
  u16* conv_w2t = (u16*)alloc(65536 * 2);
  u16* gate_w1t = (u16*)alloc(8192 * 2);

  size_t need = (size_t)(wp - (char*)d_ws);
  if (need > ws_size) {
    write_zero_f32<<<(out_size + 255) / 256, 256, 0, stream>>>((float*)d_out, out_size);
    return;
  }

  zero_counts<<<(N + 255) / 256, 256, 0, stream>>>(counts, N, gcounts, G);
  prep_weights<<<656, 256, 0, stream>>>(node_w, edge_w1, edge_w2, conv_w1, conv_w2, gate_w1,
                                        node_wt, edge_w1t, edge_w2t, conv_w1t, conv_w2t, gate_w1t);
  hist_all<<<E / 256, 256, 0, stream>>>(edst, batch, counts, gcounts, N);
  scan_a<<<49, 256, 0, stream>>>(counts, bsums, N);
  scan_b<<<1, 64, 0, stream>>>(bsums, offs, 49, N);
  scan_c<<<49, 256, 0, stream>>>(counts, bsums, offs, cursor, N);
  gscan<<<1, 256, 0, stream>>>(gcounts, goffs);
  scatter_csr<<<E / 256, 256, 0, stream>>>(esrc, edst, cursor, csr_src, csr_eid);
  node_encode<<<(N + 63) / 64, 256, 0, stream>>>(x, node_wt, node_b, hb, N);
  edge_encode<<<E / 64, 256, 0, stream>>>(edge_attr, edge_w1t, edge_w2t, edge_b1, edge_b2,
                                          csr_eid, e_perm);
  u16* hcur = hb;
  u16* hnext = hb2;
  for (int l = 0; l < 4; l++) {
    layer_k<<<(N + 63) / 64, 256, 0, stream>>>(hcur, hnext, e_perm, offs, csr_src,
                                               conv_w1t + l * 16384, conv_w2t + l * 16384,
                                               conv_b1 + l * 128, conv_b2 + l * 128,
                                               bn_gamma + l * 128, bn_beta + l * 128, N);
    u16* tmp = hcur; hcur = hnext; hnext = tmp;
  }
  gate_k<<<(N + 63) / 64, 256, 0, stream>>>(hcur, gate_w1t, gate_b1, gate_w2, gate_b2, gate, N);
  pool_k<<<G, 256, 0, stream>>>(gate, hcur, goffs, gpool);
  head_k<<<G, 128, 0, stream>>>(gpool, head_w1, head_b1, head_w2, head_b2, (float*)d_out);
}

// Round 3
// 646.162 us; speedup vs baseline: 1.0947x; 1.0140x over previous
//
#include <hip/hip_runtime.h>

typedef unsigned short u16;
typedef __bf16 bf16x8 __attribute__((ext_vector_type(8)));
typedef float f32x4 __attribute__((ext_vector_type(4)));
typedef unsigned short u16x8 __attribute__((ext_vector_type(8)));

#define NNODES 50000
#define NEDGES 640000
#define NGRAPH 256

__device__ __forceinline__ float bf2f(u16 u) {
  unsigned int v = ((unsigned int)u) << 16; float f; __builtin_memcpy(&f, &v, 4); return f;
}
__device__ __forceinline__ u16 f2bf(float f) {
  unsigned int x; __builtin_memcpy(&x, &f, 4);
  unsigned int lsb = (x >> 16) & 1u;
  x += 0x7fffu + lsb;
  return (u16)(x >> 16);
}

// ---------------- safe fallback: zero fp32 output ---------------------------
__global__ void write_zero_f32(float* __restrict__ out, int n) {
  int i = blockIdx.x * 256 + threadIdx.x;
  if (i < n) out[i] = 0.f;
}

// ---------------- weight prep + scratch zeroing (fused) ---------------------
__global__ void prep_weights(const float* __restrict__ node_w, const float* __restrict__ edge_w1,
                             const float* __restrict__ edge_w2, const float* __restrict__ conv_w1,
                             const float* __restrict__ conv_w2, const float* __restrict__ gate_w1,
                             u16* __restrict__ node_wt, u16* __restrict__ edge_w1t,
                             u16* __restrict__ edge_w2t, u16* __restrict__ conv_w1t,
                             u16* __restrict__ conv_w2t, u16* __restrict__ gate_w1t,
                             int* __restrict__ counts, int* __restrict__ gcounts) {
  int o = blockIdx.x * 256 + threadIdx.x;
  if (o < NNODES) counts[o] = 0;
  if (o < NGRAPH) gcounts[o] = 0;
  if (o < 8192) { int n = o >> 6, k = o & 63; node_wt[o] = f2bf(node_w[k * 128 + n]); return; }
  o -= 8192;
  if (o < 4096) { int n = o >> 5, k = o & 31;
                  edge_w1t[o] = (k < 16) ? f2bf(edge_w1[k * 128 + n]) : (u16)0; return; }
  o -= 4096;
  if (o < 16384) { int n = o >> 7, k = o & 127; edge_w2t[o] = f2bf(edge_w2[k * 128 + n]); return; }
  o -= 16384;
  if (o < 65536) { int l = o >> 14, r = o & 16383, n = r >> 7, k = r & 127;
                   conv_w1t[o] = f2bf(conv_w1[l * 16384 + k * 128 + n]); return; }
  o -= 65536;
  if (o < 65536) { int l = o >> 14, r = o & 16383, n = r >> 7, k = r & 127;
                   conv_w2t[o] = f2bf(conv_w2[l * 16384 + k * 128 + n]); return; }
  o -= 65536;
  if (o < 8192) { int n = o >> 7, k = o & 127; gate_w1t[o] = f2bf(gate_w1[k * 64 + n]); }
}

// ---------------- CSR build --------------------------------------------------
__global__ void hist_all(const int* __restrict__ dst, const int* __restrict__ b,
                         int* __restrict__ counts, int* __restrict__ gc, int n) {
  int i = blockIdx.x * 256 + threadIdx.x;
  atomicAdd(&counts[dst[i]], 1);
  if (i < n) atomicAdd(&gc[b[i]], 1);
}
// blocks 0..48: per-block sums of counts.  block 49: graph-offset scan.
__global__ void scan_a(const int* __restrict__ counts, int* __restrict__ bsums,
                       const int* __restrict__ gcounts, int* __restrict__ goffs, int n) {
  __shared__ int sh4[4];
  int b = blockIdx.x, t = threadIdx.x;
  int lane = t & 63, w = t >> 6;
  if (b == 49) {  // gscan
    int v = gcounts[t];
    int x = v;
    for (int d = 1; d < 64; d <<= 1) { int y = __shfl_up(x, (unsigned)d, 64); if (lane >= d) x += y; }
    if (lane == 63) sh4[w] = x;
    __syncthreads();
    int add = 0;
    for (int i = 0; i < w; i++) add += sh4[i];
    int incl = add + x;
    goffs[t] = incl - v;
    if (t == 255) goffs[256] = incl;
    return;
  }
  int i0 = b * 1024 + t * 4;
  int s = 0;
#pragma unroll
  for (int j = 0; j < 4; j++) { int i = i0 + j; if (i < n) s += counts[i]; }
  for (int m = 32; m; m >>= 1) s += __shfl_xor(s, m, 64);
  if (lane == 0) sh4[w] = s;
  __syncthreads();
  if (t == 0) bsums[b] = sh4[0] + sh4[1] + sh4[2] + sh4[3];
}
// computes its own block-offset prefix from raw bsums (scan_b removed)
__global__ void scan_c(const int* __restrict__ counts, const int* __restrict__ bsums,
                       int* __restrict__ offs, int* __restrict__ cursor, int n) {
  int b = blockIdx.x, t = threadIdx.x;
  int i0 = b * 1024 + t * 4;
  int v[4]; int s = 0;
#pragma unroll
  for (int j = 0; j < 4; j++) { v[j] = (i0 + j < n) ? counts[i0 + j] : 0; s += v[j]; }
  int lane = t & 63, w = t >> 6;
  int x = s;
  for (int d = 1; d < 64; d <<= 1) { int y = __shfl_up(x, (unsigned)d, 64); if (lane >= d) x += y; }
  __shared__ int wt_[4];
  if (lane == 63) wt_[w] = x;
  __syncthreads();
  int add = 0;
  for (int i = 0; i < b; i++) add += bsums[i];
  for (int i = 0; i < w; i++) add += wt_[i];
  int excl = add + x - s;
#pragma unroll
  for (int j = 0; j < 4; j++) {
    int i = i0 + j;
    if (i < n) { offs[i] = excl; cursor[i] = excl; }
    excl += v[j];
  }
  if (b == 0 && t == 0) offs[n] = NEDGES;
}
__global__ void scatter_csr(const int* __restrict__ src, const int* __restrict__ dst,
                            int* __restrict__ cursor, int* __restrict__ csr_src,
                            int* __restrict__ csr_eid) {
  int i = blockIdx.x * 256 + threadIdx.x;
  int d = dst[i];
  int p = atomicAdd(&cursor[d], 1);
  csr_src[p] = src[i];
  csr_eid[p] = i;
}

// ---------------- MFMA tile helper (A,B both from LDS) ----------------------
template <int KB, int SA, int SB>
__device__ __forceinline__ void mfma_block(const u16* aL, const u16* bL, int m, int quad,
                                           int rbase, f32x4* acc) {
#pragma unroll
  for (int kb = 0; kb < KB; ++kb) {
    bf16x8 a = *(const bf16x8*)(aL + (rbase + m) * SA + kb * 32 + quad * 8);
#pragma unroll
    for (int nt = 0; nt < 8; ++nt) {
      bf16x8 b = *(const bf16x8*)(bL + (nt * 16 + m) * SB + kb * 32 + quad * 8);
      acc[nt] = __builtin_amdgcn_mfma_f32_16x16x32_bf16(a, b, acc[nt], 0, 0, 0);
    }
  }
}

// ---------------- node encoder: hb = bf16(x @ node_w + node_b) --------------
__global__ __launch_bounds__(256) void node_encode(const float* __restrict__ x,
                                                   const u16* __restrict__ wt,
                                                   const float* __restrict__ nb,
                                                   u16* __restrict__ hb, int n) {
  __shared__ alignas(16) u16 sA[64 * 72];
  __shared__ alignas(16) u16 sW[128 * 72];
  int t = threadIdx.x;
  int row0 = blockIdx.x * 64;
#pragma unroll
  for (int i = 0; i < 4; i++) {
    int idx = t + 256 * i; int r = idx >> 4, c = idx & 15;  // 64 rows x 16 float4 (K=64)
    int grow = row0 + r; if (grow > n - 1) grow = n - 1;
    float4 v = *(const float4*)(x + (size_t)grow * 64 + c * 4);
    ushort4 o; o.x = f2bf(v.x); o.y = f2bf(v.y); o.z = f2bf(v.z); o.w = f2bf(v.w);
    *(ushort4*)&sA[r * 72 + c * 4] = o;
  }
#pragma unroll
  for (int i = 0; i < 4; i++) {
    int idx = t + 256 * i; int nr = idx >> 3, c = idx & 7;  // 128 rows x 8 uint4 (K=64)
    *(uint4*)&sW[nr * 72 + c * 8] = *(const uint4*)(wt + nr * 64 + c * 8);
  }
  __syncthreads();
  int lane = t & 63, w = t >> 6, m = lane & 15, quad = lane >> 4, rbase = w * 16;
  f32x4 acc[8];
  f32x4 z4 = {0.f, 0.f, 0.f, 0.f};
#pragma unroll
  for (int i = 0; i < 8; i++) acc[i] = z4;
  mfma_block<2, 72, 72>(sA, sW, m, quad, rbase, acc);
#pragma unroll
  for (int nt = 0; nt < 8; nt++) {
    int col = nt * 16 + m;
    float bb = nb[col];
    f32x4 a4 = acc[nt];
#pragma unroll
    for (int r = 0; r < 4; r++) {
      int grow = row0 + rbase + quad * 4 + r;
      if (grow < n) hb[(size_t)grow * 128 + col] = f2bf(a4[r] + bb);
    }
  }
}

// ---------------- edge encoder v10: 128-edge tiles, wave-local GEMM1 --------
// Staging + GEMM1 are wave-local (each wave stages and consumes its own 32
// edges, incl. its own K-pad zeroing) -> no barrier before GEMM1.  3 barriers
// per 128 edges (was 4 per 64).  Both GEMMs operand-swapped (D^T), uint2 LDS
// packs, coalesced 16B/lane copy-out.
__global__ __launch_bounds__(256) void edge_encode(const float* __restrict__ ea,
                                                   const u16* __restrict__ w1t,
                                                   const u16* __restrict__ w2t,
                                                   const float* __restrict__ b1,
                                                   const float* __restrict__ b2,
                                                   const int* __restrict__ csr_eid,
                                                   u16* __restrict__ e_perm) {
  __shared__ alignas(16) u16 sA[128 * 48];    // K padded 16->32
  __shared__ alignas(16) u16 sMid[128 * 136]; // GEMM1 out / GEMM2 in / out tile
  int t = threadIdx.x;
  int lane = t & 63, w = t >> 6, m = lane & 15, quad = lane >> 4;
  int s0 = blockIdx.x * 128;
  int ebase = w * 32;  // this wave's 32 edges

  // wave-local K-pad zero + ea gather (32 edges, 2 lanes/edge)
  {
    int r = lane >> 1, c = lane & 1;
    uint4 z = {0, 0, 0, 0};
    *(uint4*)&sA[(ebase + r) * 48 + 16 + c * 8] = z;
    int eidv = 0;
    if (lane < 32) eidv = csr_eid[s0 + ebase + lane];
    int eid = __shfl(eidv, r, 64);
    float4 v0 = *(const float4*)(ea + (size_t)eid * 16 + c * 8);
    float4 v1 = *(const float4*)(ea + (size_t)eid * 16 + c * 8 + 4);
    ushort4 o0; o0.x = f2bf(v0.x); o0.y = f2bf(v0.y); o0.z = f2bf(v0.z); o0.w = f2bf(v0.w);
    ushort4 o1; o1.x = f2bf(v1.x); o1.y = f2bf(v1.y); o1.z = f2bf(v1.z); o1.w = f2bf(v1.w);
    *(ushort4*)&sA[(ebase + r) * 48 + c * 8] = o0;
    *(ushort4*)&sA[(ebase + r) * 48 + c * 8 + 4] = o1;
  }
  bf16x8 w1f[8];
#pragma unroll
  for (int nt = 0; nt < 8; nt++)
    w1f[nt] = *(const bf16x8*)(w1t + (nt * 16 + m) * 32 + quad * 8);

  // GEMM1 (swapped -> D^T), wave-local: 2 row-tiles x 8 ch-tiles
  f32x4 z4 = {0.f, 0.f, 0.f, 0.f};
  f32x4 acc1[16];
#pragma unroll
  for (int i = 0; i < 16; i++) acc1[i] = z4;
#pragma unroll
  for (int rt2 = 0; rt2 < 2; rt2++) {
    bf16x8 a = *(const bf16x8*)(&sA[(ebase + rt2 * 16 + m) * 48 + quad * 8]);
#pragma unroll
    for (int nt = 0; nt < 8; nt++)
      acc1[rt2 * 8 + nt] = __builtin_amdgcn_mfma_f32_16x16x32_bf16(w1f[nt], a, acc1[rt2 * 8 + nt], 0, 0, 0);
  }
  // pack: lane holds ch nt*16+quad*4+{0..3}, edge ebase+rt2*16+m
#pragma unroll
  for (int rt2 = 0; rt2 < 2; rt2++) {
#pragma unroll
    for (int nt = 0; nt < 8; nt++) {
      float4 bb = *(const float4*)&b1[nt * 16 + quad * 4];
      f32x4 a4 = acc1[rt2 * 8 + nt];
      u16 q0 = f2bf(fmaxf(a4[0] + bb.x, 0.f));
      u16 q1 = f2bf(fmaxf(a4[1] + bb.y, 0.f));
      u16 q2 = f2bf(fmaxf(a4[2] + bb.z, 0.f));
      u16 q3 = f2bf(fmaxf(a4[3] + bb.w, 0.f));
      uint2 pk;
      pk.x = (unsigned int)q0 | ((unsigned int)q1 << 16);
      pk.y = (unsigned int)q2 | ((unsigned int)q3 << 16);
      *(uint2*)&sMid[(ebase + rt2 * 16 + m) * 136 + nt * 16 + quad * 4] = pk;
    }
  }
  bf16x8 w2f[8];
  float4 b2v[2];
#pragma unroll
  for (int ct = 0; ct < 2; ct++) {
    b2v[ct] = *(const float4*)&b2[w * 32 + ct * 16 + quad * 4];
#pragma unroll
    for (int kb = 0; kb < 4; kb++)
      w2f[ct * 4 + kb] = *(const bf16x8*)(w2t + (size_t)(w * 32 + ct * 16 + m) * 128 + kb * 32 + quad * 8);
  }
  __syncthreads();  // b2: sMid complete

  f32x4 acc2[16];
#pragma unroll
  for (int i = 0; i < 16; i++) acc2[i] = z4;
#pragma unroll
  for (int rt = 0; rt < 8; rt++) {
#pragma unroll
    for (int kb = 0; kb < 4; kb++) {
      bf16x8 a = *(const bf16x8*)(&sMid[(rt * 16 + m) * 136 + kb * 32 + quad * 8]);
      acc2[rt * 2 + 0] = __builtin_amdgcn_mfma_f32_16x16x32_bf16(w2f[kb], a, acc2[rt * 2 + 0], 0, 0, 0);
      acc2[rt * 2 + 1] = __builtin_amdgcn_mfma_f32_16x16x32_bf16(w2f[4 + kb], a, acc2[rt * 2 + 1], 0, 0, 0);
    }
  }
  __syncthreads();  // b3: all sMid reads done -> reuse as output tile
#pragma unroll
  for (int rt = 0; rt < 8; rt++) {
#pragma unroll
    for (int ct = 0; ct < 2; ct++) {
      f32x4 a4 = acc2[rt * 2 + ct];
      u16 q0 = f2bf(a4[0] + b2v[ct].x);
      u16 q1 = f2bf(a4[1] + b2v[ct].y);
      u16 q2 = f2bf(a4[2] + b2v[ct].z);
      u16 q3 = f2bf(a4[3] + b2v[ct].w);
      uint2 pk;
      pk.x = (unsigned int)q0 | ((unsigned int)q1 << 16);
      pk.y = (unsigned int)q2 | ((unsigned int)q3 << 16);
      *(uint2*)&sMid[(rt * 16 + m) * 136 + w * 32 + ct * 16 + quad * 4] = pk;
    }
  }
  __syncthreads();  // b4: out tile ready
#pragma unroll
  for (int i = 0; i < 8; i++) {
    int idx = t + 256 * i; int r = idx >> 4, c = idx & 15;
    *(uint4*)(e_perm + (size_t)(s0 + r) * 128 + c * 8) = *(const uint4*)&sMid[r * 136 + c * 8];
  }
}

// ---------------- fused layer v2: balanced aggregate + conv MLP -------------
// Phase A: wave owns 16 nodes; each node's edges are split across the wave's
// 4 quarters (slot q, q+4, ...) with cross-quarter shfl reduce -> imbalance
// is over per-wave ~205-edge sums (sigma ~7%) instead of per-quarter 51-edge
// sums (max-of-16 tail).  Phase B: conv MLP, swapped GEMMs, LDS packs.
__global__ __launch_bounds__(256) void layer_k(const u16* __restrict__ hin,
                                               u16* __restrict__ hout,
                                               const u16* __restrict__ e_perm,
                                               const int* __restrict__ offs,
                                               const int* __restrict__ csr_src,
                                               const u16* __restrict__ w1t, const u16* __restrict__ w2t,
                                               const float* __restrict__ b1, const float* __restrict__ b2,
                                               const float* __restrict__ gam, const float* __restrict__ bet,
                                               int n) {
  __shared__ alignas(16) u16 sZ[64 * 136];
  __shared__ alignas(16) u16 sMid[64 * 136];
  int t = threadIdx.x;
  int lane = t & 63, w = t >> 6, m = lane & 15, quad = lane >> 4;
  int row0 = blockIdx.x * 64;
  int li = m, q = quad;

  // ---- phase A: 16 nodes per wave, edges quarter-split ----
  for (int k = 0; k < 16; k++) {
    int lr = w * 16 + k;
    int nd = row0 + lr; if (nd > n - 1) nd = n - 1;
    int e0 = offs[nd], e1 = offs[nd + 1];
    u16x8 hv = {};
    if (q == 0) hv = *(const u16x8*)(hin + (size_t)nd * 128 + li * 8);
    float a[8];
#pragma unroll
    for (int j = 0; j < 8; j++) a[j] = 0.f;
    int s = e0 + q;
    for (; s + 8 <= e1; s += 8) {  // edges s and s+4
      int v0 = csr_src[s], v1 = csr_src[s + 4];
      u16x8 h0 = *(const u16x8*)(hin + (size_t)v0 * 128 + li * 8);
      u16x8 ee0 = *(const u16x8*)(e_perm + (size_t)s * 128 + li * 8);
      u16x8 h1 = *(const u16x8*)(hin + (size_t)v1 * 128 + li * 8);
      u16x8 ee1 = *(const u16x8*)(e_perm + (size_t)(s + 4) * 128 + li * 8);
#pragma unroll
      for (int j = 0; j < 8; j++) {
        a[j] += fmaxf(bf2f(h0[j]) + bf2f(ee0[j]), 0.f);
        a[j] += fmaxf(bf2f(h1[j]) + bf2f(ee1[j]), 0.f);
      }
    }
    for (; s < e1; s += 4) {
      int v = csr_src[s];
      u16x8 hgv = *(const u16x8*)(hin + (size_t)v * 128 + li * 8);
      u16x8 ev = *(const u16x8*)(e_perm + (size_t)s * 128 + li * 8);
#pragma unroll
      for (int j = 0; j < 8; j++) a[j] += fmaxf(bf2f(hgv[j]) + bf2f(ev[j]), 0.f);
    }
#pragma unroll
    for (int j = 0; j < 8; j++) {
      a[j] += __shfl_xor(a[j], 16, 64);
      a[j] += __shfl_xor(a[j], 32, 64);
    }
    if (q == 0) {
      u16x8 o;
#pragma unroll
      for (int j = 0; j < 8; j++) o[j] = f2bf(bf2f(hv[j]) + a[j]);
      *(u16x8*)&sZ[lr * 136 + li * 8] = o;
    }
  }
  // preload W1 fragments + bias while other waves finish aggregating
  bf16x8 w1f[8];
  float4 b1v[2];
#pragma unroll
  for (int ct = 0; ct < 2; ct++) {
    b1v[ct] = *(const float4*)&b1[w * 32 + ct * 16 + quad * 4];
#pragma unroll
    for (int kb = 0; kb < 4; kb++)
      w1f[ct * 4 + kb] = *(const bf16x8*)(w1t + (size_t)(w * 32 + ct * 16 + m) * 128 + kb * 32 + quad * 8);
  }
  __syncthreads();  // bA: sZ complete

  // ---- phase B: conv MLP (both GEMMs swapped -> D^T, LDS packs) ----
  f32x4 z4 = {0.f, 0.f, 0.f, 0.f};
  f32x4 acc[8];
#pragma unroll
  for (int i = 0; i < 8; i++) acc[i] = z4;
#pragma unroll
  for (int rt = 0; rt < 4; rt++) {
#pragma unroll
    for (int kb = 0; kb < 4; kb++) {
      bf16x8 a = *(const bf16x8*)(&sZ[(rt * 16 + m) * 136 + kb * 32 + quad * 8]);
      acc[rt * 2 + 0] = __builtin_amdgcn_mfma_f32_16x16x32_bf16(w1f[kb], a, acc[rt * 2 + 0], 0, 0, 0);
      acc[rt * 2 + 1] = __builtin_amdgcn_mfma_f32_16x16x32_bf16(w1f[4 + kb], a, acc[rt * 2 + 1], 0, 0, 0);
    }
  }
#pragma unroll
  for (int rt = 0; rt < 4; rt++) {
#pragma unroll
    for (int ct = 0; ct < 2; ct++) {
      f32x4 a4 = acc[rt * 2 + ct];
      u16 q0 = f2bf(fmaxf(a4[0] + b1v[ct].x, 0.f));
      u16 q1 = f2bf(fmaxf(a4[1] + b1v[ct].y, 0.f));
      u16 q2 = f2bf(fmaxf(a4[2] + b1v[ct].z, 0.f));
      u16 q3 = f2bf(fmaxf(a4[3] + b1v[ct].w, 0.f));
      uint2 pk;
      pk.x = (unsigned int)q0 | ((unsigned int)q1 << 16);
      pk.y = (unsigned int)q2 | ((unsigned int)q3 << 16);
      *(uint2*)&sMid[(rt * 16 + m) * 136 + w * 32 + ct * 16 + quad * 4] = pk;
    }
  }
  bf16x8 w2f[8];
  float4 b2v[2], gamv[2], betv[2];
#pragma unroll
  for (int ct = 0; ct < 2; ct++) {
    int c0 = w * 32 + ct * 16 + quad * 4;
    b2v[ct] = *(const float4*)&b2[c0];
    gamv[ct] = *(const float4*)&gam[c0];
    betv[ct] = *(const float4*)&bet[c0];
#pragma unroll
    for (int kb = 0; kb < 4; kb++)
      w2f[ct * 4 + kb] = *(const bf16x8*)(w2t + (size_t)c0 / 4 * 0 + (size_t)(w * 32 + ct * 16 + m) * 128 + kb * 32 + quad * 8);
  }
  __syncthreads();  // b2: sMid complete (sZ reads also all done)

  f32x4 acc2[8];
#pragma unroll
  for (int i = 0; i < 8; i++) acc2[i] = z4;
#pragma unroll
  for (int rt = 0; rt < 4; rt++) {
#pragma unroll
    for (int kb = 0; kb < 4; kb++) {
      bf16x8 a = *(const bf16x8*)(&sMid[(rt * 16 + m) * 136 + kb * 32 + quad * 8]);
      acc2[rt * 2 + 0] = __builtin_amdgcn_mfma_f32_16x16x32_bf16(w2f[kb], a, acc2[rt * 2 + 0], 0, 0, 0);
      acc2[rt * 2 + 1] = __builtin_amdgcn_mfma_f32_16x16x32_bf16(w2f[4 + kb], a, acc2[rt * 2 + 1], 0, 0, 0);
    }
  }
  const float bns = 0.99999500003749983f;  // 1/sqrt(1+1e-5)
  // final pack reuses sZ (its readers finished before b2)
#pragma unroll
  for (int rt = 0; rt < 4; rt++) {
#pragma unroll
    for (int ct = 0; ct < 2; ct++) {
      f32x4 a4 = acc2[rt * 2 + ct];
      u16 q0 = f2bf(fmaxf((a4[0] + b2v[ct].x) * bns * gamv[ct].x + betv[ct].x, 0.f));
      u16 q1 = f2bf(fmaxf((a4[1] + b2v[ct].y) * bns * gamv[ct].y + betv[ct].y, 0.f));
      u16 q2 = f2bf(fmaxf((a4[2] + b2v[ct].z) * bns * gamv[ct].z + betv[ct].z, 0.f));
      u16 q3 = f2bf(fmaxf((a4[3] + b2v[ct].w) * bns * gamv[ct].w + betv[ct].w, 0.f));
      uint2 pk;
      pk.x = (unsigned int)q0 | ((unsigned int)q1 << 16);
      pk.y = (unsigned int)q2 | ((unsigned int)q3 << 16);
      *(uint2*)&sZ[(rt * 16 + m) * 136 + w * 32 + ct * 16 + quad * 4] = pk;
    }
  }
  __syncthreads();  // b3: out tile ready
#pragma unroll
  for (int i = 0; i < 4; i++) {
    int idx = t + 256 * i; int r = idx >> 4, c = idx & 15;
    int grow = row0 + r;
    if (grow < n)
      *(uint4*)(hout + (size_t)grow * 128 + c * 8) = *(const uint4*)&sZ[r * 136 + c * 8];
  }
}

// ---------------- gate v2: MFMA 64-node tiles ------------------------------
__global__ __launch_bounds__(256) void gate_k(const u16* __restrict__ hb,
                                              const u16* __restrict__ w1t,
                                              const float* __restrict__ b1,
                                              const float* __restrict__ w2,
                                              const float* __restrict__ b2,
                                              float* __restrict__ gate, int n) {
  __shared__ alignas(16) u16 sA[64 * 136];
  __shared__ alignas(16) u16 sW[64 * 136];
  int t = threadIdx.x;
  int row0 = blockIdx.x * 64;
#pragma unroll
  for (int i = 0; i < 4; i++) {
    int idx = t + 256 * i; int r = idx >> 4, c = idx & 15;
    int grow = row0 + r; if (grow > n - 1) grow = n - 1;
    *(uint4*)&sA[r * 136 + c * 8] = *(const uint4*)(hb + (size_t)grow * 128 + c * 8);
  }
#pragma unroll
  for (int i = 0; i < 4; i++) {
    int idx = t + 256 * i; int r = idx >> 4, c = idx & 15;
    *(uint4*)&sW[r * 136 + c * 8] = *(const uint4*)(w1t + r * 128 + c * 8);
  }
  __syncthreads();
  int lane = t & 63, w = t >> 6, m = lane & 15, quad = lane >> 4, rbase = w * 16;
  f32x4 z4 = {0.f, 0.f, 0.f, 0.f};
  f32x4 acc[4];
#pragma unroll
  for (int i = 0; i < 4; i++) acc[i] = z4;
#pragma unroll
  for (int kb = 0; kb < 4; kb++) {
    bf16x8 a = *(const bf16x8*)(&sA[(rbase + m) * 136 + kb * 32 + quad * 8]);
#pragma unroll
    for (int nt = 0; nt < 4; nt++) {
      bf16x8 b = *(const bf16x8*)(&sW[(nt * 16 + m) * 136 + kb * 32 + quad * 8]);
      acc[nt] = __builtin_amdgcn_mfma_f32_16x16x32_bf16(a, b, acc[nt], 0, 0, 0);
    }
  }
  float b1v[4], w2v[4];
#pragma unroll
  for (int nt = 0; nt < 4; nt++) { b1v[nt] = b1[nt * 16 + m]; w2v[nt] = w2[nt * 16 + m]; }
  float b2v = b2[0];
#pragma unroll
  for (int r = 0; r < 4; r++) {
    float p = 0.f;
#pragma unroll
    for (int nt = 0; nt < 4; nt++) p += fmaxf(acc[nt][r] + b1v[nt], 0.f) * w2v[nt];
    p += __shfl_xor(p, 1, 64);
    p += __shfl_xor(p, 2, 64);
    p += __shfl_xor(p, 4, 64);
    p += __shfl_xor(p, 8, 64);
    if (m == 0) {
      int grow = row0 + rbase + quad * 4 + r;
      if (grow < n) gate[grow] = p + b2v;
    }
  }
}

// ---------------- pooled segment softmax (256 threads, parity-split) --------
__global__ __launch_bounds__(256) void pool_k(const float* __restrict__ gate,
                                              const u16* __restrict__ hb,
                                              const int* __restrict__ goffs,
                                              float* __restrict__ gpool) {
  int g = blockIdx.x, t = threadIdx.x;  // 256 threads
  int s0 = goffs[g], s1 = goffs[g + 1];
  int lane = t & 63, w = t >> 6;
  __shared__ float red[4];
  __shared__ float fin[2][128];
  float mx = -3.4e38f;
  for (int i = s0 + t; i < s1; i += 256) mx = fmaxf(mx, gate[i]);
  for (int d = 32; d; d >>= 1) mx = fmaxf(mx, __shfl_xor(mx, d, 64));
  if (lane == 0) red[w] = mx;
  __syncthreads();
  mx = fmaxf(fmaxf(red[0], red[1]), fmaxf(red[2], red[3]));
  __syncthreads();
  float sm = 0.f;
  for (int i = s0 + t; i < s1; i += 256) sm += __expf(gate[i] - mx);
  for (int d = 32; d; d >>= 1) sm += __shfl_xor(sm, d, 64);
  if (lane == 0) red[w] = sm;
  __syncthreads();
  sm = red[0] + red[1] + red[2] + red[3];
  int g2 = t >> 7, tc = t & 127;
  float acc = 0.f;
  for (int i = s0 + g2; i < s1; i += 2)
    acc += __expf(gate[i] - mx) * bf2f(hb[(size_t)i * 128 + tc]);
  fin[g2][tc] = acc;
  __syncthreads();
  if (t < 128) gpool[g * 128 + t] = (s1 > s0) ? (fin[0][t] + fin[1][t]) / sm : 0.f;
}

// ---------------- head ------------------------------------------------------
__global__ __launch_bounds__(128) void head_k(const float* __restrict__ gpool,
                                              const float* __restrict__ w1, const float* __restrict__ b1,
                                              const float* __restrict__ w2, const float* __restrict__ b2,
                                              float* __restrict__ out) {
  int g = blockIdx.x, t = threadIdx.x;  // 128
  __shared__ float sg[128];
  __shared__ float shid[128];
  sg[t] = gpool[g * 128 + t];
  __syncthreads();
  float s = 0.f;
  for (int k = 0; k < 128; k++) s += sg[k] * w1[k * 128 + t];
  shid[t] = fmaxf(s + b1[t], 0.f);
  __syncthreads();
  if (t < 5) {
    float o = b2[t];
    for (int k = 0; k < 128; k++) o += shid[k] * w2[k * 5 + t];
    out[g * 5 + t] = o;
  }
}

// ---------------- launcher ---------------------------------------------------
extern "C" void kernel_launch(void* const* d_in, const int* in_sizes, int n_in,
                              void* d_out, int out_size, void* d_ws, size_t ws_size,
                              hipStream_t stream) {
  const int N = NNODES, E = NEDGES, G = NGRAPH;
  const float* x = (const float*)d_in[0];
  const float* edge_attr = (const float*)d_in[1];
  const float* node_w = (const float*)d_in[2];
  const float* node_b = (const float*)d_in[3];
  const float* edge_w1 = (const float*)d_in[4];
  const float* edge_b1 = (const float*)d_in[5];
  const float* edge_w2 = (const float*)d_in[6];
  const float* edge_b2 = (const float*)d_in[7];
  const float* conv_w1 = (const float*)d_in[8];
  const float* conv_b1 = (const float*)d_in[9];
  const float* conv_w2 = (const float*)d_in[10];
  const float* conv_b2 = (const float*)d_in[11];
  const float* bn_gamma = (const float*)d_in[12];
  const float* bn_beta = (const float*)d_in[13];
  const float* gate_w1 = (const float*)d_in[14];
  const float* gate_b1 = (const float*)d_in[15];
  const float* gate_w2 = (const float*)d_in[16];
  const float* gate_b2 = (const float*)d_in[17];
  const float* head_w1 = (const float*)d_in[18];
  const float* head_b1 = (const float*)d_in[19];
  const float* head_w2 = (const float*)d_in[20];
  const float* head_b2 = (const float*)d_in[21];
  const int* eidx = (const int*)d_in[22];
  const int* batch = (const int*)d_in[23];
  const int* esrc = eidx;
  const int* edst = eidx + E;

  char* wp = (char*)d_ws;
  auto alloc = [&](size_t bytes) { char* p = wp; wp += (bytes + 255) & ~(size_t)255; return p; };
  u16* e_perm = (u16*)alloc((size_t)E * 128 * 2);
  u16* hb = (u16*)alloc((size_t)(N + 16) * 128 * 2);   // +pad for tile overread
  u16* hb2 = (u16*)alloc((size_t)(N + 16) * 128 * 2);  // ping-pong partner
  float* gate = (float*)alloc((size_t)N * 4);
  float* gpool = (float*)alloc((size_t)G * 128 * 4);
  int* counts = (int*)alloc((size_t)N * 4);
  int* offs = (int*)alloc((size_t)(N + 1) * 4);
  int* cursor = (int*)alloc((size_t)N * 4);
  int* csr_src = (int*)alloc((size_t)E * 4);
  int* csr_eid = (int*)alloc((size_t)E * 4);
  int* bsums = (int*)alloc(64 * 4);
  int* gcounts = (int*)alloc(G * 4);
  int* goffs = (int*)alloc((G + 1) * 4);
  u16* node_wt = (u16*)alloc(8192 * 2);
  u16* edge_w1t = (u16*)alloc(4096 * 2);
  u16* edge_w2t = (u16*)alloc(16384 * 2);
  u16* conv_w1t = (u16*)alloc(65536 * 2);
  u16* conv_w2t = (u16*)alloc(65536 * 2);
  u16* gate_w1t = (u16*)alloc(8192 * 2);

  size_t need = (size_t)(wp - (char*)d_ws);
  if (need > ws_size) {
    write_zero_f32<<<(out_size + 255) / 256, 256, 0, stream>>>((float*)d_out, out_size);
    return;
  }

  prep_weights<<<656, 256, 0, stream>>>(node_w, edge_w1, edge_w2, conv_w1, conv_w2, gate_w1,
                                        node_wt, edge_w1t, edge_w2t, conv_w1t, conv_w2t, gate_w1t,
                                        counts, gcounts);
  hist_all<<<E / 256, 256, 0, stream>>>(edst, batch, counts, gcounts, N);
  scan_a<<<50, 256, 0, stream>>>(counts, bsums, gcounts, goffs, N);
  scan_c<<<49, 256, 0, stream>>>(counts, bsums, offs, cursor, N);
  scatter_csr<<<E / 256, 256, 0, stream>>>(esrc, edst, cursor, csr_src, csr_eid);
  node_encode<<<(N + 63) / 64, 256, 0, stream>>>(x, node_wt, node_b, hb, N);
  edge_encode<<<E / 128, 256, 0, stream>>>(edge_attr, edge_w1t, edge_w2t, edge_b1, edge_b2,
                                           csr_eid, e_perm);
  u16* hcur = hb;
  u16* hnext = hb2;
  for (int l = 0; l < 4; l++) {
    layer_k<<<(N + 63) / 64, 256, 0, stream>>>(hcur, hnext, e_perm, offs, csr_src,
                                               conv_w1t + l * 16384, conv_w2t + l * 16384,
                                               conv_b1 + l * 128, conv_b2 + l * 128,
                                               bn_gamma + l * 128, bn_beta + l * 128, N);
    u16* tmp = hcur; hcur = hnext; hnext = tmp;
  }
  gate_k<<<(N + 63) / 64, 256, 0, stream>>>(hcur, gate_w1t, gate_b1, gate_w2, gate_b2, gate, N);
  pool_k<<<G, 256, 0, stream>>>(gate, hcur, goffs, gpool);
  head_k<<<G, 128, 0, stream>>>(gpool, head_w1, head_b1, head_w2, head_b2, (float*)d_out);
}